// Round 10
// baseline (21185.999 us; speedup 1.0000x reference)
//
#include <hip/hip_runtime.h>
#include <hip/hip_fp16.h>
#include <math.h>

namespace {
constexpr int Bn  = 512;
constexpr int Tn  = 100;
constexpr int Hn  = 256;
constexpr int En  = 256;
constexpr int D2n = 512;
constexpr int G4n = 1024;
constexpr float PENf = 1e6f;
constexpr size_t BIGN = (size_t)Bn * Tn * D2n;   // 26,214,400 elements
constexpr size_t SMALL_BYTES =
    ((size_t)2 * Bn * G4n + 5 * Bn * D2n + 3 * Bn * Tn + 4 * Bn * Hn + 4 * G4n) * 4;
}

using short8  = __attribute__((ext_vector_type(8))) short;
using floatx4 = __attribute__((ext_vector_type(4))) float;

// ---- type conversion helpers ----------------------------------------------
template<typename T> __device__ __forceinline__ float cvt_to_f(T x);
template<> __device__ __forceinline__ float cvt_to_f<float>(float x) { return x; }
template<> __device__ __forceinline__ float cvt_to_f<__half>(__half x) {
  return __half2float(x);
}
template<typename T> __device__ __forceinline__ T cvt_from_f(float x);
template<> __device__ __forceinline__ float cvt_from_f<float>(float x) { return x; }
template<> __device__ __forceinline__ __half cvt_from_f<__half>(float x) {
  return __float2half(x);
}
__device__ __forceinline__ float h2f_bits(unsigned short b) {
  __half_raw r; r.x = b; return __half2float(__half(r));
}
template<typename T> __device__ __forceinline__ float4 load4(const T* p);
template<> __device__ __forceinline__ float4 load4<float>(const float* p) {
  return *(const float4*)p;
}
template<> __device__ __forceinline__ float4 load4<__half>(const __half* p) {
  const ushort4 u = *(const ushort4*)p;
  float4 r;
  r.x = h2f_bits(u.x); r.y = h2f_bits(u.y);
  r.z = h2f_bits(u.z); r.w = h2f_bits(u.w);
  return r;
}
__device__ __forceinline__ float sigmoidf(float x) {
  return 1.0f / (1.0f + expf(-x));
}
__device__ __forceinline__ float fast_tanhf(float x) {
  return 1.0f - 2.0f / (__expf(2.0f * x) + 1.0f);
}

// ---- device-scope (sc1) coherent accessors for DYNAMIC buffers ------------
// agent-scope relaxed atomics lower to global_load/store with device-scope
// cache bits: bypass non-coherent L1/L2, hit the LLC coherence point.
__device__ __forceinline__ float loadf_dev(const float* p) {
  return __uint_as_float(__hip_atomic_load((const unsigned*)p, __ATOMIC_RELAXED,
                                           __HIP_MEMORY_SCOPE_AGENT));
}
__device__ __forceinline__ void storef_dev(float* p, float v) {
  __hip_atomic_store((unsigned*)p, __float_as_uint(v), __ATOMIC_RELAXED,
                     __HIP_MEMORY_SCOPE_AGENT);
}
__device__ __forceinline__ float4 load4_dev(const float* p) {
  const unsigned long long a = __hip_atomic_load((const unsigned long long*)p,
      __ATOMIC_RELAXED, __HIP_MEMORY_SCOPE_AGENT);
  const unsigned long long b = __hip_atomic_load((const unsigned long long*)p + 1,
      __ATOMIC_RELAXED, __HIP_MEMORY_SCOPE_AGENT);
  float4 r;
  r.x = __uint_as_float((unsigned)a);  r.y = __uint_as_float((unsigned)(a >> 32));
  r.z = __uint_as_float((unsigned)b);  r.w = __uint_as_float((unsigned)(b >> 32));
  return r;
}
__device__ __forceinline__ void store4_dev(float* p, const float4 v) {
  const unsigned long long a = (unsigned long long)__float_as_uint(v.x) |
                               ((unsigned long long)__float_as_uint(v.y) << 32);
  const unsigned long long b = (unsigned long long)__float_as_uint(v.z) |
                               ((unsigned long long)__float_as_uint(v.w) << 32);
  __hip_atomic_store((unsigned long long*)p, a, __ATOMIC_RELAXED,
                     __HIP_MEMORY_SCOPE_AGENT);
  __hip_atomic_store((unsigned long long*)p + 1, b, __ATOMIC_RELAXED,
                     __HIP_MEMORY_SCOPE_AGENT);
}
template<typename CT> __device__ __forceinline__ CT load_dev(const CT* p);
template<> __device__ __forceinline__ float load_dev<float>(const float* p) {
  return loadf_dev(p);
}
template<> __device__ __forceinline__ __half load_dev<__half>(const __half* p) {
  unsigned short u = __hip_atomic_load((const unsigned short*)p, __ATOMIC_RELAXED,
                                       __HIP_MEMORY_SCOPE_AGENT);
  __half_raw r; r.x = u; return (__half)r;
}
template<typename CT> __device__ __forceinline__ void store_dev(CT* p, CT v);
template<> __device__ __forceinline__ void store_dev<float>(float* p, float v) {
  storef_dev(p, v);
}
template<> __device__ __forceinline__ void store_dev<__half>(__half* p, __half v) {
  __half_raw r = *reinterpret_cast<__half_raw*>(&v);
  __hip_atomic_store((unsigned short*)p, r.x, __ATOMIC_RELAXED,
                     __HIP_MEMORY_SCOPE_AGENT);
}

// fp32 -> (hi bf16 truncate, lo bf16 rne of residual)
__device__ __forceinline__ void split2(float x, short& h, short& l) {
  const unsigned u  = __float_as_uint(x);
  const unsigned hu = u & 0xffff0000u;
  h = (short)(hu >> 16);
  const float r = x - __uint_as_float(hu);
  l = (short)((__float_as_uint(r) + 0x8000u) >> 16);
}
__device__ __forceinline__ void store4split(const float4 v, short* hp, short* lp) {
  short h0, h1, h2, h3, l0, l1, l2, l3;
  split2(v.x, h0, l0); split2(v.y, h1, l1);
  split2(v.z, h2, l2); split2(v.w, h3, l3);
  *(short4*)hp = make_short4(h0, h1, h2, h3);
  *(short4*)lp = make_short4(l0, l1, l2, l3);
}

// ---- manual grid barrier (256 blocks, 1/CU co-resident) -------------------
// Coherence of cross-block data moved to per-access sc1; NO acquire fence
// (keeps L2 warm for read-only weights/refs/Enc). Release fence stays: with
// sc1 stores the dirty-L2 set is ~empty, so wbl2 is cheap.
__device__ __forceinline__ void grid_sync(unsigned* cnt, unsigned target) {
  __syncthreads();   // implicit s_waitcnt vmcnt(0): drains sc1 stores to LLC
  if (threadIdx.x == 0) {
    __builtin_amdgcn_fence(__ATOMIC_RELEASE, "agent");
    __hip_atomic_fetch_add(cnt, 1u, __ATOMIC_RELAXED, __HIP_MEMORY_SCOPE_AGENT);
    while (__hip_atomic_load(cnt, __ATOMIC_RELAXED,
                             __HIP_MEMORY_SCOPE_AGENT) < target)
      __builtin_amdgcn_s_sleep(1);
  }
  __syncthreads();
}

// ---------------------------------------------------------------------------
// Pipelined 64xN GEMM: C (+)= A[64,K]*B[N,K]^T, split-bf16 MFMA (hh,hl,lh).
// A is DYNAMIC (sc1 loads); B is static (plain cached). CSC: C via sc1.
// ---------------------------------------------------------------------------
template<typename CT, bool ACC, int NT, bool CSC>
__device__ __forceinline__ void gemm64v2(short* smem,
    const float* A, int lda, int m0,
    const float* B, int ldb, int n0, int K,
    CT* Cbase, size_t crstride, int tid) {
  constexpr int BPL  = NT * 128;             // B kgroup stride (shorts)
  constexpr int BSZ  = NT * 512;             // B plane size (shorts)
  constexpr int BUFS = 4096 + 2 * BSZ;       // shorts per LDS buffer
  const int lane = tid & 63, wave = tid >> 6, qm = lane & 15, quad = lane >> 4;
  const int ra = tid >> 3, c4 = tid & 7, j0 = (c4 & 1) * 4, gq = c4 >> 1;
  const int a0 = gq * 512 + ra * 8 + j0;
  const int a1 = gq * 512 + (ra + 32) * 8 + j0;
  const int b0 = gq * BPL + ra * 8 + j0;
  const int b1 = gq * BPL + (ra + 32) * 8 + j0;
  const int CN = K >> 5;

  floatx4 acc[NT];
#pragma unroll
  for (int nt = 0; nt < NT; ++nt) acc[nt] = (floatx4){0.f, 0.f, 0.f, 0.f};

  float4 Aa0, Aa1, Ba0, Ba1, Ab0, Ab1, Bb0, Bb1;
  auto ld = [&](int c, float4& x0, float4& x1, float4& y0, float4& y1) {
    const int k0 = c * 32 + c4 * 4;
    x0 = load4_dev(A + (size_t)(m0 + ra) * lda + k0);
    x1 = load4_dev(A + (size_t)(m0 + ra + 32) * lda + k0);
    y0 = *(const float4*)(B + (size_t)(n0 + ra) * ldb + k0);
    if (NT == 4)
      y1 = *(const float4*)(B + (size_t)(n0 + ra + 32) * ldb + k0);
  };
  auto st = [&](short* bp, const float4& x0, const float4& x1,
                const float4& y0, const float4& y1) {
    store4split(x0, bp + a0, bp + 2048 + a0);
    store4split(x1, bp + a1, bp + 2048 + a1);
    store4split(y0, bp + 4096 + b0, bp + 4096 + BSZ + b0);
    if (NT == 4) store4split(y1, bp + 4096 + b1, bp + 4096 + BSZ + b1);
  };
  auto mm = [&](const short* bp) {
    const int abase = quad * 512 + (wave * 16 + qm) * 8;
    const short8 ah = *(const short8*)&bp[abase];
    const short8 al = *(const short8*)&bp[2048 + abase];
#pragma unroll
    for (int nt = 0; nt < NT; ++nt) {
      const int bb = quad * BPL + (nt * 16 + qm) * 8;
      const short8 bh = *(const short8*)&bp[4096 + bb];
      const short8 bl = *(const short8*)&bp[4096 + BSZ + bb];
      acc[nt] = __builtin_amdgcn_mfma_f32_16x16x32_bf16(ah, bh, acc[nt], 0, 0, 0);
      acc[nt] = __builtin_amdgcn_mfma_f32_16x16x32_bf16(ah, bl, acc[nt], 0, 0, 0);
      acc[nt] = __builtin_amdgcn_mfma_f32_16x16x32_bf16(al, bh, acc[nt], 0, 0, 0);
    }
  };

  ld(0, Aa0, Aa1, Ba0, Ba1);
  if (CN > 1) ld(1, Ab0, Ab1, Bb0, Bb1);
  st(smem, Aa0, Aa1, Ba0, Ba1);
  __syncthreads();
  for (int c = 0; c < CN; c += 2) {
    if (c + 2 < CN) ld(c + 2, Aa0, Aa1, Ba0, Ba1);
    mm(smem);
    if (c + 1 < CN) st(smem + BUFS, Ab0, Ab1, Bb0, Bb1);
    __syncthreads();
    if (c + 1 < CN) {
      if (c + 3 < CN) ld(c + 3, Ab0, Ab1, Bb0, Bb1);
      mm(smem + BUFS);
      if (c + 2 < CN) st(smem, Aa0, Aa1, Ba0, Ba1);
      __syncthreads();
    }
  }

#pragma unroll
  for (int nt = 0; nt < NT; ++nt)
#pragma unroll
    for (int r2 = 0; r2 < 4; ++r2) {
      const int m = wave * 16 + quad * 4 + r2, n = nt * 16 + qm;
      CT* cp = Cbase + (size_t)m * crstride + n;
      float o = acc[nt][r2];
      if (CSC) {
        if (ACC) o += cvt_to_f<CT>(load_dev<CT>(cp));
        store_dev<CT>(cp, cvt_from_f<CT>(o));
      } else {
        if (ACC) o += cvt_to_f<CT>(*cp);
        *cp = cvt_from_f<CT>(o);
      }
    }
}

// ---------------------------------------------------------------------------
// Pipelined gate GEMM: 4 accs (i,f,g,o), out tile 64(m) x 16(h-slice)/gate.
// A segments are DYNAMIC (sc1); B weights static (plain, stay L2-resident).
// ---------------------------------------------------------------------------
__device__ __forceinline__ void gates_gemm_v2(floatx4 acc[4], short* smem,
    const float* A1, int lda1, const float* B1, int ldb1, int K1,
    const float* A2, int lda2, const float* B2, int ldb2, int K2,
    int m0, int hoff, int tid) {
  const int lane = tid & 63, wave = tid >> 6, qm = lane & 15, quad = lane >> 4;
  const int ra = tid >> 3, c4 = tid & 7, j0 = (c4 & 1) * 4, gq = c4 >> 1;
  const int a0 = gq * 512 + ra * 8 + j0;
  const int a1 = gq * 512 + (ra + 32) * 8 + j0;
  const int g0 = (ra >> 4) * Hn + hoff + (ra & 15);
  const int g1 = ((ra + 32) >> 4) * Hn + hoff + ((ra + 32) & 15);
  const int C1 = K1 >> 5;
  const int C2 = A2 ? (K2 >> 5) : 0;
  const int CN = C1 + C2;

  float4 Aa0, Aa1, Ba0, Ba1, Ab0, Ab1, Bb0, Bb1;
  auto ld = [&](int c, float4& x0, float4& x1, float4& y0, float4& y1) {
    const float* A; const float* B; int lda, ldb, k0;
    if (c < C1) { A = A1; B = B1; lda = lda1; ldb = ldb1; k0 = c * 32; }
    else        { A = A2; B = B2; lda = lda2; ldb = ldb2; k0 = (c - C1) * 32; }
    k0 += c4 * 4;
    x0 = load4_dev(A + (size_t)(m0 + ra) * lda + k0);
    x1 = load4_dev(A + (size_t)(m0 + ra + 32) * lda + k0);
    y0 = *(const float4*)(B + (size_t)g0 * ldb + k0);
    y1 = *(const float4*)(B + (size_t)g1 * ldb + k0);
  };
  auto st2 = [&](short* bp, const float4& x0, const float4& x1,
                 const float4& y0, const float4& y1) {
    store4split(x0, bp + a0, bp + 2048 + a0);
    store4split(x1, bp + a1, bp + 2048 + a1);
    store4split(y0, bp + 4096 + a0, bp + 6144 + a0);
    store4split(y1, bp + 4096 + a1, bp + 6144 + a1);
  };
  auto mm = [&](const short* bp) {
    const int abase = quad * 512 + (wave * 16 + qm) * 8;
    const short8 ah = *(const short8*)&bp[abase];
    const short8 al = *(const short8*)&bp[2048 + abase];
#pragma unroll
    for (int gg = 0; gg < 4; ++gg) {
      const int bb = quad * 512 + (gg * 16 + qm) * 8;
      const short8 bh = *(const short8*)&bp[4096 + bb];
      const short8 bl = *(const short8*)&bp[6144 + bb];
      acc[gg] = __builtin_amdgcn_mfma_f32_16x16x32_bf16(ah, bh, acc[gg], 0, 0, 0);
      acc[gg] = __builtin_amdgcn_mfma_f32_16x16x32_bf16(ah, bl, acc[gg], 0, 0, 0);
      acc[gg] = __builtin_amdgcn_mfma_f32_16x16x32_bf16(al, bh, acc[gg], 0, 0, 0);
    }
  };

  if (CN <= 0) return;
  ld(0, Aa0, Aa1, Ba0, Ba1);
  if (CN > 1) ld(1, Ab0, Ab1, Bb0, Bb1);
  st2(smem, Aa0, Aa1, Ba0, Ba1);
  __syncthreads();
  for (int c = 0; c < CN; c += 2) {
    if (c + 2 < CN) ld(c + 2, Aa0, Aa1, Ba0, Ba1);
    mm(smem);
    if (c + 1 < CN) st2(smem + 8192, Ab0, Ab1, Bb0, Bb1);
    __syncthreads();
    if (c + 1 < CN) {
      if (c + 3 < CN) ld(c + 3, Ab0, Ab1, Bb0, Bb1);
      mm(smem + 8192);
      if (c + 2 < CN) st2(smem, Aa0, Aa1, Ba0, Ba1);
      __syncthreads();
    }
  }
}

// ---------------------------------------------------------------------------
__global__ void weff_kernel(const float* Wih_f, const float* Wih_b,
                            const float* W_embed, float* weff_f, float* weff_b) {
  const int gidx = blockIdx.x * 256 + threadIdx.x;
  if (gidx >= G4n) return;
  float f0 = 0.f, f1 = 0.f, b0 = 0.f, b1 = 0.f;
  for (int e = 0; e < En; ++e) {
    const float w0 = W_embed[e * 2 + 0];
    const float w1 = W_embed[e * 2 + 1];
    const float wf = Wih_f[gidx * En + e];
    const float wb = Wih_b[gidx * En + e];
    f0 = fmaf(wf, w0, f0); f1 = fmaf(wf, w1, f1);
    b0 = fmaf(wb, w0, b0); b1 = fmaf(wb, w1, b1);
  }
  weff_f[gidx * 2 + 0] = f0; weff_f[gidx * 2 + 1] = f1;
  weff_b[gidx * 2 + 0] = b0; weff_b[gidx * 2 + 1] = b1;
}

// ---------------------------------------------------------------------------
// Persistent encoder: 100 steps, 1 grid-sync/step. 256 blocks.
// ---------------------------------------------------------------------------
template<typename ET, typename RT1, typename RT2>
struct EncP {
  const float* inputs;
  const float* Whh_f; const float* Whh_b;
  const float* b_f; const float* b_b;
  const float* weff_f; const float* weff_b;
  const float* W_ref; const float* W_ref2;
  float* hbuf;       // [2 parity][2 dir][512*256]  (dynamic, sc1)
  float* c_dec;      // [2 dir][512*256]            (kernel-boundary)
  float* dec_out0;   // [512*512]                   (kernel-boundary)
  ET* Enc; RT1* ref1; RT2* ref2;
  unsigned* barrier;
};

template<typename ET, typename RT1, typename RT2>
__global__ __launch_bounds__(256, 1) void enc_coop(EncP<ET, RT1, RT2> P) {
  __shared__ __align__(16) short smem[16384];
  const int bid = blockIdx.x, tid = threadIdx.x;
  const int dir = bid >> 7, btile = (bid >> 4) & 7, hs = bid & 15;
  const int r_ref = (bid >> 7) & 1, r_dir = (bid >> 6) & 1;
  const int r_bt = (bid >> 3) & 7, r_ns = bid & 7;
  const int lane = tid & 63, wave = tid >> 6, qm = lane & 15, quad = lane >> 4;
  const int hcol = hs * 16 + qm;
  const float* Whh  = dir ? P.Whh_b : P.Whh_f;
  const float* bias = dir ? P.b_b : P.b_f;
  const float* weff = dir ? P.weff_b : P.weff_f;
  float c_reg[4] = {0.f, 0.f, 0.f, 0.f};
  float h_reg[4] = {0.f, 0.f, 0.f, 0.f};
  unsigned sync_no = 0;

  auto ref_job = [&](const float* hpar, int pos) {
    const float* hsrc = hpar + (size_t)r_dir * (Bn * Hn);
    if (r_ref == 0)
      gemm64v2<RT1, true, 4, true>(smem, hsrc, Hn, r_bt * 64,
                             P.W_ref + r_dir * Hn, D2n, r_ns * 64, Hn,
                             P.ref1 + (size_t)(r_bt * 64) * Tn * D2n + (size_t)pos * D2n + r_ns * 64,
                             (size_t)Tn * D2n, tid);
    else
      gemm64v2<RT2, true, 4, true>(smem, hsrc, Hn, r_bt * 64,
                             P.W_ref2 + r_dir * Hn, D2n, r_ns * 64, Hn,
                             P.ref2 + (size_t)(r_bt * 64) * Tn * D2n + (size_t)pos * D2n + r_ns * 64,
                             (size_t)Tn * D2n, tid);
  };

  for (int t = 0; t < Tn; ++t) {
    const float* hprev = P.hbuf + (size_t)((t - 1) & 1) * (2 * Bn * Hn);
    if (t > 0) ref_job(hprev, r_dir ? (Tn - t) : (t - 1));
    floatx4 acc[4];
#pragma unroll
    for (int gg = 0; gg < 4; ++gg) acc[gg] = (floatx4){0.f, 0.f, 0.f, 0.f};
    if (t > 0)
      gates_gemm_v2(acc, smem, hprev + (size_t)dir * (Bn * Hn), Hn, Whh, Hn, Hn,
                    nullptr, 0, nullptr, 0, 0, btile * 64, hs * 16, tid);
    const int tcur = dir ? (Tn - 1 - t) : t;
    float xa[4], xb2[4];
#pragma unroll
    for (int r2 = 0; r2 < 4; ++r2) {
      const int m = btile * 64 + wave * 16 + quad * 4 + r2;
      xa[r2]  = P.inputs[(size_t)m * (Tn * 2) + tcur * 2 + 0];
      xb2[r2] = P.inputs[(size_t)m * (Tn * 2) + tcur * 2 + 1];
    }
    float gv[4][4];
#pragma unroll
    for (int gg = 0; gg < 4; ++gg) {
      const int grow = gg * Hn + hcol;
      const float bn = bias[grow];
      const float w20 = weff[grow * 2], w21 = weff[grow * 2 + 1];
#pragma unroll
      for (int r2 = 0; r2 < 4; ++r2) {
        float o = acc[gg][r2] + bn;
        o = fmaf(xa[r2], w20, fmaf(xb2[r2], w21, o));
        gv[gg][r2] = o;
      }
    }
    float* hdst = P.hbuf + (size_t)(t & 1) * (2 * Bn * Hn) + (size_t)dir * (Bn * Hn);
    const int tt = dir ? (Tn - 1 - t) : t;
#pragma unroll
    for (int r2 = 0; r2 < 4; ++r2) {
      const float cn = sigmoidf(gv[1][r2]) * c_reg[r2] +
                       sigmoidf(gv[0][r2]) * tanhf(gv[2][r2]);
      c_reg[r2] = cn;
      const float hn = sigmoidf(gv[3][r2]) * tanhf(cn);
      h_reg[r2] = hn;
      const int m = btile * 64 + wave * 16 + quad * 4 + r2;
      storef_dev(&hdst[(size_t)m * Hn + hcol], hn);
      store_dev<ET>(&P.Enc[(size_t)m * Tn * D2n + (size_t)tt * D2n + dir * Hn + hcol],
                    cvt_from_f<ET>(hn));
    }
    grid_sync(P.barrier, 256u * (++sync_no));
  }
  ref_job(P.hbuf + (size_t)1 * (2 * Bn * Hn), r_dir ? 0 : (Tn - 1));
#pragma unroll
  for (int r2 = 0; r2 < 4; ++r2) {
    const int m = btile * 64 + wave * 16 + quad * 4 + r2;
    P.dec_out0[(size_t)m * D2n + dir * Hn + hcol] = h_reg[r2];
    P.c_dec[((size_t)dir * Bn + m) * Hn + hcol] = c_reg[r2];
  }
}

// ---------------------------------------------------------------------------
// Persistent decoder: 100 steps, 3 grid-syncs/step. 256 blocks.
// ---------------------------------------------------------------------------
template<typename ET, typename RT1, typename RT2>
struct DecP {
  const int* test_roads;
  const float* Wih_f; const float* Whh_f; const float* b_f;
  const float* Wih_b; const float* Whh_b; const float* b_b;
  const float* W_q; const float* W_q2; const float* v; const float* v2;
  const ET* Enc; const RT1* ref1; const RT2* ref2;
  float* dec_out;    // [2][512*512] (dynamic, sc1)
  float* xb;         // [2][512*512] (dynamic, sc1)
  float* qb; float* q2b;            // (dynamic, sc1)
  const float* c_init;  // [2][512*256] (kernel-boundary)
  float* loss;       // d_out [512]
  unsigned* barrier;
};

template<typename ET, typename RT1, typename RT2>
__global__ __launch_bounds__(256, 1) void dec_coop(DecP<ET, RT1, RT2> P) {
  __shared__ __align__(16) short smem[16384];
  __shared__ float s1l[2][104], s2l[2][104];
  __shared__ float awl[2][104];
  __shared__ float redf[2][128];
  __shared__ int   redi[2][128];
  __shared__ float playedl[2][104];
  __shared__ float lossl[2];
  const int bid = blockIdx.x, tid = threadIdx.x;
  const int dir = bid >> 7, btile = (bid >> 4) & 7, hs = bid & 15;
  const int lane = tid & 63, wave = tid >> 6, qm = lane & 15, quad = lane >> 4;
  const int hcol = hs * 16 + qm;
  const float* Wih  = dir ? P.Wih_b : P.Wih_f;
  const float* Whh  = dir ? P.Whh_b : P.Whh_f;
  const float* bias = dir ? P.b_b : P.b_f;
  float c_reg[4];
#pragma unroll
  for (int r2 = 0; r2 < 4; ++r2) {
    const int m = btile * 64 + wave * 16 + quad * 4 + r2;
    c_reg[r2] = P.c_init[((size_t)dir * Bn + m) * Hn + hcol];
  }
  if (tid < Tn) { playedl[0][tid] = 0.f; playedl[1][tid] = 0.f; }
  if (tid < 2) lossl[tid] = 0.f;
  // P2: 256 jobs of 64x32
  const int proj = bid >> 7, pbt = (bid >> 4) & 7, pn = bid & 15;
  // P3 mapping: wave -> (local b, attn)
  const int ab = wave >> 1, attn = wave & 1;
  const int gb = bid * 2 + ab;
  const int half = tid >> 7, htid = tid & 127;
  unsigned sync_no = 0;
  __syncthreads();

  for (int t = 0; t < Tn; ++t) {
    const float* xc  = P.xb + (size_t)(t & 1) * (Bn * D2n);
    const float* dcur = P.dec_out + (size_t)(t & 1) * (Bn * D2n);
    float* dnext = P.dec_out + (size_t)((t + 1) & 1) * (Bn * D2n);
    // ---- P1: cell gates + LSTM ----
    floatx4 acc[4];
#pragma unroll
    for (int gg = 0; gg < 4; ++gg) acc[gg] = (floatx4){0.f, 0.f, 0.f, 0.f};
    gates_gemm_v2(acc, smem, xc, D2n, Wih, D2n, D2n,
                  dcur + dir * Hn, D2n, Whh, Hn, Hn, btile * 64, hs * 16, tid);
#pragma unroll
    for (int gg = 0; gg < 4; ++gg) {
      const float bn = bias[gg * Hn + hcol];
#pragma unroll
      for (int r2 = 0; r2 < 4; ++r2) acc[gg][r2] += bn;
    }
#pragma unroll
    for (int r2 = 0; r2 < 4; ++r2) {
      const float cn = sigmoidf(acc[1][r2]) * c_reg[r2] +
                       sigmoidf(acc[0][r2]) * tanhf(acc[2][r2]);
      c_reg[r2] = cn;
      const float hn = sigmoidf(acc[3][r2]) * tanhf(cn);
      const int m = btile * 64 + wave * 16 + quad * 4 + r2;
      storef_dev(&dnext[(size_t)m * D2n + dir * Hn + hcol], hn);
    }
    grid_sync(P.barrier, 256u * (++sync_no));
    // ---- P2: q projections (256 jobs, 64x32 tiles) ----
    {
      const float* A = proj ? xc : dnext;
      const float* B = proj ? P.W_q2 : P.W_q;
      float* C = (proj ? P.q2b : P.qb) + (size_t)(pbt * 64) * D2n + pn * 32;
      gemm64v2<float, false, 2, true>(smem, A, D2n, pbt * 64, B, D2n, pn * 32, D2n,
                                      C, D2n, tid);
    }
    grid_sync(P.barrier, 256u * (++sync_no));
    // ---- P3: attention, 10-row groups, static ping-pong prefetch ----
    {
      const float* qrow = (attn ? P.q2b : P.qb) + (size_t)gb * D2n;
      const float* vp = attn ? P.v2 : P.v;
      const int e0 = lane * 4, e1 = (64 + lane) * 4;
      const float4 q0 = load4_dev(qrow + e0);
      const float4 q1 = load4_dev(qrow + e1);
      const float4 v0 = *(const float4*)&vp[e0];
      const float4 v1 = *(const float4*)&vp[e1];
      float* sdst = attn ? &s2l[ab][0] : &s1l[ab][0];
      float4 Ra0[10], Ra1[10], Rb0[10], Rb1[10];
      auto ldg = [&](int jb, float4 (&R0)[10], float4 (&R1)[10]) {
#pragma unroll
        for (int jj = 0; jj < 10; ++jj) {
          if (attn == 0) {
            const RT1* row = P.ref1 + ((size_t)gb * Tn + jb + jj) * D2n;
            R0[jj] = load4<RT1>(row + e0); R1[jj] = load4<RT1>(row + e1);
          } else {
            const RT2* row = P.ref2 + ((size_t)gb * Tn + jb + jj) * D2n;
            R0[jj] = load4<RT2>(row + e0); R1[jj] = load4<RT2>(row + e1);
          }
        }
      };
      auto cmp = [&](int jb, const float4 (&R0)[10], const float4 (&R1)[10]) {
#pragma unroll
        for (int jj = 0; jj < 10; ++jj) {
          const float4 r0 = R0[jj], r1 = R1[jj];
          float a = 0.f;
          a = fmaf(fast_tanhf(r0.x + q0.x), v0.x, a);
          a = fmaf(fast_tanhf(r0.y + q0.y), v0.y, a);
          a = fmaf(fast_tanhf(r0.z + q0.z), v0.z, a);
          a = fmaf(fast_tanhf(r0.w + q0.w), v0.w, a);
          a = fmaf(fast_tanhf(r1.x + q1.x), v1.x, a);
          a = fmaf(fast_tanhf(r1.y + q1.y), v1.y, a);
          a = fmaf(fast_tanhf(r1.z + q1.z), v1.z, a);
          a = fmaf(fast_tanhf(r1.w + q1.w), v1.w, a);
#pragma unroll
          for (int off = 32; off > 0; off >>= 1) a += __shfl_xor(a, off, 64);
          if (lane == 0) sdst[jb + jj] = a;
        }
      };
      ldg(0, Ra0, Ra1);
      for (int g = 0; g < 10; g += 2) {
        if (g + 1 < 10) ldg((g + 1) * 10, Rb0, Rb1);
        cmp(g * 10, Ra0, Ra1);
        if (g + 2 < 10) ldg((g + 2) * 10, Ra0, Ra1);
        if (g + 1 < 10) cmp((g + 1) * 10, Rb0, Rb1);
      }
    }
    __syncthreads();
    // ---- P4: both owned b's in parallel on half-blocks ----
    {
      float* xnextbuf = P.xb + (size_t)((t + 1) & 1) * (Bn * D2n);
      const int b = bid * 2 + half;
      float* rf = &redf[half][0];
      int*   ri = &redi[half][0];
      const float uval = (htid < Tn) ? s2l[half][htid] : -INFINITY;
      const float owval = (htid < Tn) ? (s1l[half][htid] - PENf * playedl[half][htid])
                                      : -INFINITY;
      rf[htid] = uval; __syncthreads();
      for (int s = 64; s > 0; s >>= 1) {
        if (htid < s) rf[htid] = fmaxf(rf[htid], rf[htid + s]);
        __syncthreads();
      }
      const float umax = rf[0]; __syncthreads();
      const float e = (htid < Tn) ? __expf(uval - umax) : 0.f;
      rf[htid] = e; __syncthreads();
      for (int s = 64; s > 0; s >>= 1) {
        if (htid < s) rf[htid] += rf[htid + s];
        __syncthreads();
      }
      const float usum = rf[0]; __syncthreads();
      if (htid < Tn) awl[half][htid] = e / usum;
      rf[htid] = owval; ri[htid] = (htid < Tn) ? htid : 0x7fffffff; __syncthreads();
      for (int s = 64; s > 0; s >>= 1) {
        if (htid < s) {
          const float ov = rf[htid + s]; const int oi = ri[htid + s];
          if (ov > rf[htid] || (ov == rf[htid] && oi < ri[htid])) {
            rf[htid] = ov; ri[htid] = oi;
          }
        }
        __syncthreads();
      }
      const float omax = rf[0]; const int sel = ri[0]; __syncthreads();
      const float eo = (htid < Tn) ? __expf(owval - omax) : 0.f;
      rf[htid] = eo; __syncthreads();
      for (int s = 64; s > 0; s >>= 1) {
        if (htid < s) rf[htid] += rf[htid + s];
        __syncthreads();
      }
      if (htid == 0) {
        const float lse = omax + __logf(rf[0]);
        const int tgt = P.test_roads[b * Tn + t];
        const float owt = s1l[half][tgt] - PENf * playedl[half][tgt];
        lossl[half] += lse - owt;
        playedl[half][sel] += 1.f;
      }
      __syncthreads();
      // x_new: per-thread float4 over 4 cols, 10-row groups, static ping-pong
      const ET* Eb = P.Enc + (size_t)b * Tn * D2n;
      float* xn = xnextbuf + (size_t)b * D2n;
      const int k4 = htid * 4;            // 128 threads * 4 = 512 cols
      float4 Ea[10], Eb2[10];
      auto lde = [&](int jb, float4 (&E)[10]) {
#pragma unroll
        for (int jj = 0; jj < 10; ++jj)
          E[jj] = load4<ET>(Eb + (size_t)(jb + jj) * D2n + k4);
      };
      float4 a4 = {0.f, 0.f, 0.f, 0.f};
      auto ac4 = [&](int jb, const float4 (&E)[10]) {
#pragma unroll
        for (int jj = 0; jj < 10; ++jj) {
          const float w = awl[half][jb + jj];
          a4.x = fmaf(w, E[jj].x, a4.x);
          a4.y = fmaf(w, E[jj].y, a4.y);
          a4.z = fmaf(w, E[jj].z, a4.z);
          a4.w = fmaf(w, E[jj].w, a4.w);
        }
      };
      lde(0, Ea);
      for (int g = 0; g < 10; g += 2) {
        if (g + 1 < 10) lde((g + 1) * 10, Eb2);
        ac4(g * 10, Ea);
        if (g + 2 < 10) lde((g + 2) * 10, Ea);
        if (g + 1 < 10) ac4((g + 1) * 10, Eb2);
      }
      store4_dev(&xn[k4], a4);
    }
    grid_sync(P.barrier, 256u * (++sync_no));
  }
  if (tid == 0) {
    P.loss[bid * 2]     = lossl[0];
    P.loss[bid * 2 + 1] = lossl[1];
  }
}

// ---------------------------------------------------------------------------
template<typename ET, typename RT1, typename RT2>
static void run_all(void* const* d_in, void* d_out, char* ws, hipStream_t stream) {
  const float* inputs     = (const float*)d_in[0];
  const int*   test_roads = (const int*)d_in[1];
  const float* W_embed    = (const float*)d_in[2];
  const float* enc_Wih_f  = (const float*)d_in[3];
  const float* enc_Whh_f  = (const float*)d_in[4];
  const float* enc_b_f    = (const float*)d_in[5];
  const float* enc_Wih_b  = (const float*)d_in[6];
  const float* enc_Whh_b  = (const float*)d_in[7];
  const float* enc_b_b    = (const float*)d_in[8];
  const float* dec_Wih_f  = (const float*)d_in[9];
  const float* dec_Whh_f  = (const float*)d_in[10];
  const float* dec_b_f    = (const float*)d_in[11];
  const float* dec_Wih_b  = (const float*)d_in[12];
  const float* dec_Whh_b  = (const float*)d_in[13];
  const float* dec_b_b    = (const float*)d_in[14];
  const float* W_ref      = (const float*)d_in[15];
  const float* W_q        = (const float*)d_in[16];
  const float* v          = (const float*)d_in[17];
  const float* W_ref2     = (const float*)d_in[18];
  const float* W_q2       = (const float*)d_in[19];
  const float* v2         = (const float*)d_in[20];

  char* p0 = ws;
  ET*  Enc  = (ET*)p0;  p0 += BIGN * sizeof(ET);
  RT1* ref1 = (RT1*)p0; p0 += BIGN * sizeof(RT1);
  RT2* ref2 = (RT2*)p0; p0 += BIGN * sizeof(RT2);
  unsigned* barrier = (unsigned*)p0;                   // 256 B reserved
  float* xb      = (float*)(p0 + 256);                 // 2 * 512*512
  float* dec_out = xb + 2 * Bn * D2n;                  // 2 * 512*512
  float* hbuf    = dec_out + 2 * Bn * D2n;             // 2 * 2 * 512*256
  float* c_dec   = hbuf + 4 * Bn * Hn;                 // 2 * 512*256
  float* qb      = c_dec + 2 * Bn * Hn;
  float* q2b     = qb + Bn * D2n;
  float* weff_f  = q2b + Bn * D2n;
  float* weff_b  = weff_f + G4n * 2;

  hipMemsetAsync(ref1, 0, BIGN * (sizeof(RT1) + sizeof(RT2)), stream);
  hipMemsetAsync(barrier, 0, 256 + (size_t)Bn * D2n * 4, stream);

  weff_kernel<<<G4n / 256, 256, 0, stream>>>(enc_Wih_f, enc_Wih_b, W_embed,
                                             weff_f, weff_b);

  EncP<ET, RT1, RT2> ep = { inputs, enc_Whh_f, enc_Whh_b, enc_b_f, enc_b_b,
                            weff_f, weff_b, W_ref, W_ref2,
                            hbuf, c_dec, dec_out, Enc, ref1, ref2, barrier };
  enc_coop<ET, RT1, RT2><<<256, 256, 0, stream>>>(ep);

  DecP<ET, RT1, RT2> dp = { test_roads,
                            dec_Wih_f, dec_Whh_f, dec_b_f,
                            dec_Wih_b, dec_Whh_b, dec_b_b,
                            W_q, W_q2, v, v2,
                            Enc, ref1, ref2,
                            dec_out, xb, qb, q2b, c_dec,
                            (float*)d_out, barrier + 1 };
  dec_coop<ET, RT1, RT2><<<256, 256, 0, stream>>>(dp);
}

// ---------------------------------------------------------------------------
extern "C" void kernel_launch(void* const* d_in, const int* in_sizes, int n_in,
                              void* d_out, int out_size, void* d_ws, size_t ws_size,
                              hipStream_t stream) {
  (void)in_sizes; (void)n_in; (void)out_size;
  char* ws = (char*)d_ws;
  const size_t szA = 3 * BIGN * 4 + SMALL_BYTES;               // all f32
  const size_t szB = 2 * BIGN * 4 + BIGN * 2 + SMALL_BYTES;    // Enc f16
  const size_t szC = BIGN * 4 + 2 * BIGN * 2 + SMALL_BYTES;    // + ref2 f16
  if (ws_size >= szA)      run_all<float,  float,  float >(d_in, d_out, ws, stream);
  else if (ws_size >= szB) run_all<__half, float,  float >(d_in, d_out, ws, stream);
  else if (ws_size >= szC) run_all<__half, float,  __half>(d_in, d_out, ws, stream);
  else                     run_all<__half, __half, __half>(d_in, d_out, ws, stream);
}

// Round 11
// 19342.403 us; speedup vs baseline: 1.0953x; 1.0953x over previous
//
#include <hip/hip_runtime.h>
#include <hip/hip_fp16.h>
#include <math.h>

namespace {
constexpr int Bn  = 512;
constexpr int Tn  = 100;
constexpr int Hn  = 256;
constexpr int En  = 256;
constexpr int D2n = 512;
constexpr int G4n = 1024;
constexpr float PENf = 1e6f;
constexpr size_t BIGN = (size_t)Bn * Tn * D2n;   // 26,214,400 elements
constexpr size_t SMALL_BYTES =
    ((size_t)2 * Bn * G4n + 5 * Bn * D2n + 3 * Bn * Tn + 4 * Bn * Hn + 4 * G4n) * 4;
}

using short8  = __attribute__((ext_vector_type(8))) short;
using floatx4 = __attribute__((ext_vector_type(4))) float;

// ---- type conversion helpers ----------------------------------------------
template<typename T> __device__ __forceinline__ float cvt_to_f(T x);
template<> __device__ __forceinline__ float cvt_to_f<float>(float x) { return x; }
template<> __device__ __forceinline__ float cvt_to_f<__half>(__half x) {
  return __half2float(x);
}
template<typename T> __device__ __forceinline__ T cvt_from_f(float x);
template<> __device__ __forceinline__ float cvt_from_f<float>(float x) { return x; }
template<> __device__ __forceinline__ __half cvt_from_f<__half>(float x) {
  return __float2half(x);
}
__device__ __forceinline__ float h2f_bits(unsigned short b) {
  __half_raw r; r.x = b; return __half2float(__half(r));
}
template<typename T> __device__ __forceinline__ float4 load4(const T* p);
template<> __device__ __forceinline__ float4 load4<float>(const float* p) {
  return *(const float4*)p;
}
template<> __device__ __forceinline__ float4 load4<__half>(const __half* p) {
  const ushort4 u = *(const ushort4*)p;
  float4 r;
  r.x = h2f_bits(u.x); r.y = h2f_bits(u.y);
  r.z = h2f_bits(u.z); r.w = h2f_bits(u.w);
  return r;
}
__device__ __forceinline__ float sigmoidf(float x) {
  return 1.0f / (1.0f + expf(-x));
}
__device__ __forceinline__ float fast_tanhf(float x) {
  return 1.0f - 2.0f / (__expf(2.0f * x) + 1.0f);
}

// ---- device-scope (sc1) coherent accessors for DYNAMIC buffers ------------
// agent-scope relaxed atomics lower to global_load/store with device-scope
// cache bits: bypass non-coherent L1/L2, hit the LLC coherence point.
__device__ __forceinline__ float loadf_dev(const float* p) {
  return __uint_as_float(__hip_atomic_load((const unsigned*)p, __ATOMIC_RELAXED,
                                           __HIP_MEMORY_SCOPE_AGENT));
}
__device__ __forceinline__ void storef_dev(float* p, float v) {
  __hip_atomic_store((unsigned*)p, __float_as_uint(v), __ATOMIC_RELAXED,
                     __HIP_MEMORY_SCOPE_AGENT);
}
__device__ __forceinline__ float4 load4_dev(const float* p) {
  const unsigned long long a = __hip_atomic_load((const unsigned long long*)p,
      __ATOMIC_RELAXED, __HIP_MEMORY_SCOPE_AGENT);
  const unsigned long long b = __hip_atomic_load((const unsigned long long*)p + 1,
      __ATOMIC_RELAXED, __HIP_MEMORY_SCOPE_AGENT);
  float4 r;
  r.x = __uint_as_float((unsigned)a);  r.y = __uint_as_float((unsigned)(a >> 32));
  r.z = __uint_as_float((unsigned)b);  r.w = __uint_as_float((unsigned)(b >> 32));
  return r;
}
__device__ __forceinline__ void store4_dev(float* p, const float4 v) {
  const unsigned long long a = (unsigned long long)__float_as_uint(v.x) |
                               ((unsigned long long)__float_as_uint(v.y) << 32);
  const unsigned long long b = (unsigned long long)__float_as_uint(v.z) |
                               ((unsigned long long)__float_as_uint(v.w) << 32);
  __hip_atomic_store((unsigned long long*)p, a, __ATOMIC_RELAXED,
                     __HIP_MEMORY_SCOPE_AGENT);
  __hip_atomic_store((unsigned long long*)p + 1, b, __ATOMIC_RELAXED,
                     __HIP_MEMORY_SCOPE_AGENT);
}
template<typename CT> __device__ __forceinline__ CT load_dev(const CT* p);
template<> __device__ __forceinline__ float load_dev<float>(const float* p) {
  return loadf_dev(p);
}
template<> __device__ __forceinline__ __half load_dev<__half>(const __half* p) {
  unsigned short u = __hip_atomic_load((const unsigned short*)p, __ATOMIC_RELAXED,
                                       __HIP_MEMORY_SCOPE_AGENT);
  __half_raw r; r.x = u; return (__half)r;
}
template<typename CT> __device__ __forceinline__ void store_dev(CT* p, CT v);
template<> __device__ __forceinline__ void store_dev<float>(float* p, float v) {
  storef_dev(p, v);
}
template<> __device__ __forceinline__ void store_dev<__half>(__half* p, __half v) {
  __half_raw r = *reinterpret_cast<__half_raw*>(&v);
  __hip_atomic_store((unsigned short*)p, r.x, __ATOMIC_RELAXED,
                     __HIP_MEMORY_SCOPE_AGENT);
}

// fp32 -> (hi bf16 truncate, lo bf16 rne of residual)
__device__ __forceinline__ void split2(float x, short& h, short& l) {
  const unsigned u  = __float_as_uint(x);
  const unsigned hu = u & 0xffff0000u;
  h = (short)(hu >> 16);
  const float r = x - __uint_as_float(hu);
  l = (short)((__float_as_uint(r) + 0x8000u) >> 16);
}
__device__ __forceinline__ void store4split(const float4 v, short* hp, short* lp) {
  short h0, h1, h2, h3, l0, l1, l2, l3;
  split2(v.x, h0, l0); split2(v.y, h1, l1);
  split2(v.z, h2, l2); split2(v.w, h3, l3);
  *(short4*)hp = make_short4(h0, h1, h2, h3);
  *(short4*)lp = make_short4(l0, l1, l2, l3);
}

// ---- manual grid barrier (256 blocks, 1/CU co-resident) -------------------
// NO release fence: all cross-block data moves via sc1 (LLC = coherence
// point) and the explicit s_waitcnt(0) in EVERY thread guarantees its sc1
// stores have reached the LLC before it arrives at s_barrier; block 0's
// flag-add therefore happens after all data is globally visible. Consumers
// read via sc1, so no invalidate (acquire) is needed either. This removes
// the per-block buffer_wbl2 L2-walk (~20 µs/barrier, serialized per XCD)
// that the agent-scope release fence emits on multi-XCD gfx950.
__device__ __forceinline__ void grid_sync(unsigned* cnt, unsigned target) {
  __builtin_amdgcn_s_waitcnt(0);   // drain vm/lgkm: sc1 stores now at LLC
  __syncthreads();
  if (threadIdx.x == 0) {
    __hip_atomic_fetch_add(cnt, 1u, __ATOMIC_RELAXED, __HIP_MEMORY_SCOPE_AGENT);
    while (__hip_atomic_load(cnt, __ATOMIC_RELAXED,
                             __HIP_MEMORY_SCOPE_AGENT) < target)
      __builtin_amdgcn_s_sleep(1);
  }
  __syncthreads();
}

// ---------------------------------------------------------------------------
// Pipelined 64xN GEMM: C (+)= A[64,K]*B[N,K]^T, split-bf16 MFMA (hh,hl,lh).
// A is DYNAMIC (sc1 loads); B is static (plain cached). CSC: C via sc1.
// ---------------------------------------------------------------------------
template<typename CT, bool ACC, int NT, bool CSC>
__device__ __forceinline__ void gemm64v2(short* smem,
    const float* A, int lda, int m0,
    const float* B, int ldb, int n0, int K,
    CT* Cbase, size_t crstride, int tid) {
  constexpr int BPL  = NT * 128;             // B kgroup stride (shorts)
  constexpr int BSZ  = NT * 512;             // B plane size (shorts)
  constexpr int BUFS = 4096 + 2 * BSZ;       // shorts per LDS buffer
  const int lane = tid & 63, wave = tid >> 6, qm = lane & 15, quad = lane >> 4;
  const int ra = tid >> 3, c4 = tid & 7, j0 = (c4 & 1) * 4, gq = c4 >> 1;
  const int a0 = gq * 512 + ra * 8 + j0;
  const int a1 = gq * 512 + (ra + 32) * 8 + j0;
  const int b0 = gq * BPL + ra * 8 + j0;
  const int b1 = gq * BPL + (ra + 32) * 8 + j0;
  const int CN = K >> 5;

  floatx4 acc[NT];
#pragma unroll
  for (int nt = 0; nt < NT; ++nt) acc[nt] = (floatx4){0.f, 0.f, 0.f, 0.f};

  float4 Aa0, Aa1, Ba0, Ba1, Ab0, Ab1, Bb0, Bb1;
  auto ld = [&](int c, float4& x0, float4& x1, float4& y0, float4& y1) {
    const int k0 = c * 32 + c4 * 4;
    x0 = load4_dev(A + (size_t)(m0 + ra) * lda + k0);
    x1 = load4_dev(A + (size_t)(m0 + ra + 32) * lda + k0);
    y0 = *(const float4*)(B + (size_t)(n0 + ra) * ldb + k0);
    if (NT == 4)
      y1 = *(const float4*)(B + (size_t)(n0 + ra + 32) * ldb + k0);
  };
  auto st = [&](short* bp, const float4& x0, const float4& x1,
                const float4& y0, const float4& y1) {
    store4split(x0, bp + a0, bp + 2048 + a0);
    store4split(x1, bp + a1, bp + 2048 + a1);
    store4split(y0, bp + 4096 + b0, bp + 4096 + BSZ + b0);
    if (NT == 4) store4split(y1, bp + 4096 + b1, bp + 4096 + BSZ + b1);
  };
  auto mm = [&](const short* bp) {
    const int abase = quad * 512 + (wave * 16 + qm) * 8;
    const short8 ah = *(const short8*)&bp[abase];
    const short8 al = *(const short8*)&bp[2048 + abase];
#pragma unroll
    for (int nt = 0; nt < NT; ++nt) {
      const int bb = quad * BPL + (nt * 16 + qm) * 8;
      const short8 bh = *(const short8*)&bp[4096 + bb];
      const short8 bl = *(const short8*)&bp[4096 + BSZ + bb];
      acc[nt] = __builtin_amdgcn_mfma_f32_16x16x32_bf16(ah, bh, acc[nt], 0, 0, 0);
      acc[nt] = __builtin_amdgcn_mfma_f32_16x16x32_bf16(ah, bl, acc[nt], 0, 0, 0);
      acc[nt] = __builtin_amdgcn_mfma_f32_16x16x32_bf16(al, bh, acc[nt], 0, 0, 0);
    }
  };

  ld(0, Aa0, Aa1, Ba0, Ba1);
  if (CN > 1) ld(1, Ab0, Ab1, Bb0, Bb1);
  st(smem, Aa0, Aa1, Ba0, Ba1);
  __syncthreads();
  for (int c = 0; c < CN; c += 2) {
    if (c + 2 < CN) ld(c + 2, Aa0, Aa1, Ba0, Ba1);
    mm(smem);
    if (c + 1 < CN) st(smem + BUFS, Ab0, Ab1, Bb0, Bb1);
    __syncthreads();
    if (c + 1 < CN) {
      if (c + 3 < CN) ld(c + 3, Ab0, Ab1, Bb0, Bb1);
      mm(smem + BUFS);
      if (c + 2 < CN) st(smem, Aa0, Aa1, Ba0, Ba1);
      __syncthreads();
    }
  }

#pragma unroll
  for (int nt = 0; nt < NT; ++nt)
#pragma unroll
    for (int r2 = 0; r2 < 4; ++r2) {
      const int m = wave * 16 + quad * 4 + r2, n = nt * 16 + qm;
      CT* cp = Cbase + (size_t)m * crstride + n;
      float o = acc[nt][r2];
      if (CSC) {
        if (ACC) o += cvt_to_f<CT>(load_dev<CT>(cp));
        store_dev<CT>(cp, cvt_from_f<CT>(o));
      } else {
        if (ACC) o += cvt_to_f<CT>(*cp);
        *cp = cvt_from_f<CT>(o);
      }
    }
}

// ---------------------------------------------------------------------------
// Pipelined gate GEMM: 4 accs (i,f,g,o), out tile 64(m) x 16(h-slice)/gate.
// A segments are DYNAMIC (sc1); B weights static (plain, stay L2-resident).
// ---------------------------------------------------------------------------
__device__ __forceinline__ void gates_gemm_v2(floatx4 acc[4], short* smem,
    const float* A1, int lda1, const float* B1, int ldb1, int K1,
    const float* A2, int lda2, const float* B2, int ldb2, int K2,
    int m0, int hoff, int tid) {
  const int lane = tid & 63, wave = tid >> 6, qm = lane & 15, quad = lane >> 4;
  const int ra = tid >> 3, c4 = tid & 7, j0 = (c4 & 1) * 4, gq = c4 >> 1;
  const int a0 = gq * 512 + ra * 8 + j0;
  const int a1 = gq * 512 + (ra + 32) * 8 + j0;
  const int g0 = (ra >> 4) * Hn + hoff + (ra & 15);
  const int g1 = ((ra + 32) >> 4) * Hn + hoff + ((ra + 32) & 15);
  const int C1 = K1 >> 5;
  const int C2 = A2 ? (K2 >> 5) : 0;
  const int CN = C1 + C2;

  float4 Aa0, Aa1, Ba0, Ba1, Ab0, Ab1, Bb0, Bb1;
  auto ld = [&](int c, float4& x0, float4& x1, float4& y0, float4& y1) {
    const float* A; const float* B; int lda, ldb, k0;
    if (c < C1) { A = A1; B = B1; lda = lda1; ldb = ldb1; k0 = c * 32; }
    else        { A = A2; B = B2; lda = lda2; ldb = ldb2; k0 = (c - C1) * 32; }
    k0 += c4 * 4;
    x0 = load4_dev(A + (size_t)(m0 + ra) * lda + k0);
    x1 = load4_dev(A + (size_t)(m0 + ra + 32) * lda + k0);
    y0 = *(const float4*)(B + (size_t)g0 * ldb + k0);
    y1 = *(const float4*)(B + (size_t)g1 * ldb + k0);
  };
  auto st2 = [&](short* bp, const float4& x0, const float4& x1,
                 const float4& y0, const float4& y1) {
    store4split(x0, bp + a0, bp + 2048 + a0);
    store4split(x1, bp + a1, bp + 2048 + a1);
    store4split(y0, bp + 4096 + a0, bp + 6144 + a0);
    store4split(y1, bp + 4096 + a1, bp + 6144 + a1);
  };
  auto mm = [&](const short* bp) {
    const int abase = quad * 512 + (wave * 16 + qm) * 8;
    const short8 ah = *(const short8*)&bp[abase];
    const short8 al = *(const short8*)&bp[2048 + abase];
#pragma unroll
    for (int gg = 0; gg < 4; ++gg) {
      const int bb = quad * 512 + (gg * 16 + qm) * 8;
      const short8 bh = *(const short8*)&bp[4096 + bb];
      const short8 bl = *(const short8*)&bp[6144 + bb];
      acc[gg] = __builtin_amdgcn_mfma_f32_16x16x32_bf16(ah, bh, acc[gg], 0, 0, 0);
      acc[gg] = __builtin_amdgcn_mfma_f32_16x16x32_bf16(ah, bl, acc[gg], 0, 0, 0);
      acc[gg] = __builtin_amdgcn_mfma_f32_16x16x32_bf16(al, bh, acc[gg], 0, 0, 0);
    }
  };

  if (CN <= 0) return;
  ld(0, Aa0, Aa1, Ba0, Ba1);
  if (CN > 1) ld(1, Ab0, Ab1, Bb0, Bb1);
  st2(smem, Aa0, Aa1, Ba0, Ba1);
  __syncthreads();
  for (int c = 0; c < CN; c += 2) {
    if (c + 2 < CN) ld(c + 2, Aa0, Aa1, Ba0, Ba1);
    mm(smem);
    if (c + 1 < CN) st2(smem + 8192, Ab0, Ab1, Bb0, Bb1);
    __syncthreads();
    if (c + 1 < CN) {
      if (c + 3 < CN) ld(c + 3, Ab0, Ab1, Bb0, Bb1);
      mm(smem + 8192);
      if (c + 2 < CN) st2(smem, Aa0, Aa1, Ba0, Ba1);
      __syncthreads();
    }
  }
}

// ---------------------------------------------------------------------------
__global__ void weff_kernel(const float* Wih_f, const float* Wih_b,
                            const float* W_embed, float* weff_f, float* weff_b) {
  const int gidx = blockIdx.x * 256 + threadIdx.x;
  if (gidx >= G4n) return;
  float f0 = 0.f, f1 = 0.f, b0 = 0.f, b1 = 0.f;
  for (int e = 0; e < En; ++e) {
    const float w0 = W_embed[e * 2 + 0];
    const float w1 = W_embed[e * 2 + 1];
    const float wf = Wih_f[gidx * En + e];
    const float wb = Wih_b[gidx * En + e];
    f0 = fmaf(wf, w0, f0); f1 = fmaf(wf, w1, f1);
    b0 = fmaf(wb, w0, b0); b1 = fmaf(wb, w1, b1);
  }
  weff_f[gidx * 2 + 0] = f0; weff_f[gidx * 2 + 1] = f1;
  weff_b[gidx * 2 + 0] = b0; weff_b[gidx * 2 + 1] = b1;
}

// ---------------------------------------------------------------------------
// Persistent encoder: 100 steps, 1 grid-sync/step. 256 blocks.
// ---------------------------------------------------------------------------
template<typename ET, typename RT1, typename RT2>
struct EncP {
  const float* inputs;
  const float* Whh_f; const float* Whh_b;
  const float* b_f; const float* b_b;
  const float* weff_f; const float* weff_b;
  const float* W_ref; const float* W_ref2;
  float* hbuf;       // [2 parity][2 dir][512*256]  (dynamic, sc1)
  float* c_dec;      // [2 dir][512*256]            (kernel-boundary)
  float* dec_out0;   // [512*512]                   (kernel-boundary)
  ET* Enc; RT1* ref1; RT2* ref2;
  unsigned* barrier;
};

template<typename ET, typename RT1, typename RT2>
__global__ __launch_bounds__(256, 1) void enc_coop(EncP<ET, RT1, RT2> P) {
  __shared__ __align__(16) short smem[16384];
  const int bid = blockIdx.x, tid = threadIdx.x;
  const int dir = bid >> 7, btile = (bid >> 4) & 7, hs = bid & 15;
  const int r_ref = (bid >> 7) & 1, r_dir = (bid >> 6) & 1;
  const int r_bt = (bid >> 3) & 7, r_ns = bid & 7;
  const int lane = tid & 63, wave = tid >> 6, qm = lane & 15, quad = lane >> 4;
  const int hcol = hs * 16 + qm;
  const float* Whh  = dir ? P.Whh_b : P.Whh_f;
  const float* bias = dir ? P.b_b : P.b_f;
  const float* weff = dir ? P.weff_b : P.weff_f;
  float c_reg[4] = {0.f, 0.f, 0.f, 0.f};
  float h_reg[4] = {0.f, 0.f, 0.f, 0.f};
  unsigned sync_no = 0;

  auto ref_job = [&](const float* hpar, int pos) {
    const float* hsrc = hpar + (size_t)r_dir * (Bn * Hn);
    if (r_ref == 0)
      gemm64v2<RT1, true, 4, true>(smem, hsrc, Hn, r_bt * 64,
                             P.W_ref + r_dir * Hn, D2n, r_ns * 64, Hn,
                             P.ref1 + (size_t)(r_bt * 64) * Tn * D2n + (size_t)pos * D2n + r_ns * 64,
                             (size_t)Tn * D2n, tid);
    else
      gemm64v2<RT2, true, 4, true>(smem, hsrc, Hn, r_bt * 64,
                             P.W_ref2 + r_dir * Hn, D2n, r_ns * 64, Hn,
                             P.ref2 + (size_t)(r_bt * 64) * Tn * D2n + (size_t)pos * D2n + r_ns * 64,
                             (size_t)Tn * D2n, tid);
  };

  for (int t = 0; t < Tn; ++t) {
    const float* hprev = P.hbuf + (size_t)((t - 1) & 1) * (2 * Bn * Hn);
    if (t > 0) ref_job(hprev, r_dir ? (Tn - t) : (t - 1));
    floatx4 acc[4];
#pragma unroll
    for (int gg = 0; gg < 4; ++gg) acc[gg] = (floatx4){0.f, 0.f, 0.f, 0.f};
    if (t > 0)
      gates_gemm_v2(acc, smem, hprev + (size_t)dir * (Bn * Hn), Hn, Whh, Hn, Hn,
                    nullptr, 0, nullptr, 0, 0, btile * 64, hs * 16, tid);
    const int tcur = dir ? (Tn - 1 - t) : t;
    float xa[4], xb2[4];
#pragma unroll
    for (int r2 = 0; r2 < 4; ++r2) {
      const int m = btile * 64 + wave * 16 + quad * 4 + r2;
      xa[r2]  = P.inputs[(size_t)m * (Tn * 2) + tcur * 2 + 0];
      xb2[r2] = P.inputs[(size_t)m * (Tn * 2) + tcur * 2 + 1];
    }
    float gv[4][4];
#pragma unroll
    for (int gg = 0; gg < 4; ++gg) {
      const int grow = gg * Hn + hcol;
      const float bn = bias[grow];
      const float w20 = weff[grow * 2], w21 = weff[grow * 2 + 1];
#pragma unroll
      for (int r2 = 0; r2 < 4; ++r2) {
        float o = acc[gg][r2] + bn;
        o = fmaf(xa[r2], w20, fmaf(xb2[r2], w21, o));
        gv[gg][r2] = o;
      }
    }
    float* hdst = P.hbuf + (size_t)(t & 1) * (2 * Bn * Hn) + (size_t)dir * (Bn * Hn);
    const int tt = dir ? (Tn - 1 - t) : t;
#pragma unroll
    for (int r2 = 0; r2 < 4; ++r2) {
      const float cn = sigmoidf(gv[1][r2]) * c_reg[r2] +
                       sigmoidf(gv[0][r2]) * tanhf(gv[2][r2]);
      c_reg[r2] = cn;
      const float hn = sigmoidf(gv[3][r2]) * tanhf(cn);
      h_reg[r2] = hn;
      const int m = btile * 64 + wave * 16 + quad * 4 + r2;
      storef_dev(&hdst[(size_t)m * Hn + hcol], hn);
      store_dev<ET>(&P.Enc[(size_t)m * Tn * D2n + (size_t)tt * D2n + dir * Hn + hcol],
                    cvt_from_f<ET>(hn));
    }
    grid_sync(P.barrier, 256u * (++sync_no));
  }
  ref_job(P.hbuf + (size_t)1 * (2 * Bn * Hn), r_dir ? 0 : (Tn - 1));
#pragma unroll
  for (int r2 = 0; r2 < 4; ++r2) {
    const int m = btile * 64 + wave * 16 + quad * 4 + r2;
    P.dec_out0[(size_t)m * D2n + dir * Hn + hcol] = h_reg[r2];
    P.c_dec[((size_t)dir * Bn + m) * Hn + hcol] = c_reg[r2];
  }
}

// ---------------------------------------------------------------------------
// Persistent decoder: 100 steps, 3 grid-syncs/step. 256 blocks.
// ---------------------------------------------------------------------------
template<typename ET, typename RT1, typename RT2>
struct DecP {
  const int* test_roads;
  const float* Wih_f; const float* Whh_f; const float* b_f;
  const float* Wih_b; const float* Whh_b; const float* b_b;
  const float* W_q; const float* W_q2; const float* v; const float* v2;
  const ET* Enc; const RT1* ref1; const RT2* ref2;
  float* dec_out;    // [2][512*512] (dynamic, sc1)
  float* xb;         // [2][512*512] (dynamic, sc1)
  float* qb; float* q2b;            // (dynamic, sc1)
  const float* c_init;  // [2][512*256] (kernel-boundary)
  float* loss;       // d_out [512]
  unsigned* barrier;
};

template<typename ET, typename RT1, typename RT2>
__global__ __launch_bounds__(256, 1) void dec_coop(DecP<ET, RT1, RT2> P) {
  __shared__ __align__(16) short smem[16384];
  __shared__ float s1l[2][104], s2l[2][104];
  __shared__ float awl[2][104];
  __shared__ float redf[2][128];
  __shared__ int   redi[2][128];
  __shared__ float playedl[2][104];
  __shared__ float lossl[2];
  const int bid = blockIdx.x, tid = threadIdx.x;
  const int dir = bid >> 7, btile = (bid >> 4) & 7, hs = bid & 15;
  const int lane = tid & 63, wave = tid >> 6, qm = lane & 15, quad = lane >> 4;
  const int hcol = hs * 16 + qm;
  const float* Wih  = dir ? P.Wih_b : P.Wih_f;
  const float* Whh  = dir ? P.Whh_b : P.Whh_f;
  const float* bias = dir ? P.b_b : P.b_f;
  float c_reg[4];
#pragma unroll
  for (int r2 = 0; r2 < 4; ++r2) {
    const int m = btile * 64 + wave * 16 + quad * 4 + r2;
    c_reg[r2] = P.c_init[((size_t)dir * Bn + m) * Hn + hcol];
  }
  if (tid < Tn) { playedl[0][tid] = 0.f; playedl[1][tid] = 0.f; }
  if (tid < 2) lossl[tid] = 0.f;
  // P2: 256 jobs of 64x32
  const int proj = bid >> 7, pbt = (bid >> 4) & 7, pn = bid & 15;
  // P3 mapping: wave -> (local b, attn)
  const int ab = wave >> 1, attn = wave & 1;
  const int gb = bid * 2 + ab;
  const int half = tid >> 7, htid = tid & 127;
  unsigned sync_no = 0;
  __syncthreads();

  for (int t = 0; t < Tn; ++t) {
    const float* xc  = P.xb + (size_t)(t & 1) * (Bn * D2n);
    const float* dcur = P.dec_out + (size_t)(t & 1) * (Bn * D2n);
    float* dnext = P.dec_out + (size_t)((t + 1) & 1) * (Bn * D2n);
    // ---- P1: cell gates + LSTM ----
    floatx4 acc[4];
#pragma unroll
    for (int gg = 0; gg < 4; ++gg) acc[gg] = (floatx4){0.f, 0.f, 0.f, 0.f};
    gates_gemm_v2(acc, smem, xc, D2n, Wih, D2n, D2n,
                  dcur + dir * Hn, D2n, Whh, Hn, Hn, btile * 64, hs * 16, tid);
#pragma unroll
    for (int gg = 0; gg < 4; ++gg) {
      const float bn = bias[gg * Hn + hcol];
#pragma unroll
      for (int r2 = 0; r2 < 4; ++r2) acc[gg][r2] += bn;
    }
#pragma unroll
    for (int r2 = 0; r2 < 4; ++r2) {
      const float cn = sigmoidf(acc[1][r2]) * c_reg[r2] +
                       sigmoidf(acc[0][r2]) * tanhf(acc[2][r2]);
      c_reg[r2] = cn;
      const float hn = sigmoidf(acc[3][r2]) * tanhf(cn);
      const int m = btile * 64 + wave * 16 + quad * 4 + r2;
      storef_dev(&dnext[(size_t)m * D2n + dir * Hn + hcol], hn);
    }
    grid_sync(P.barrier, 256u * (++sync_no));
    // ---- P2: q projections (256 jobs, 64x32 tiles) ----
    {
      const float* A = proj ? xc : dnext;
      const float* B = proj ? P.W_q2 : P.W_q;
      float* C = (proj ? P.q2b : P.qb) + (size_t)(pbt * 64) * D2n + pn * 32;
      gemm64v2<float, false, 2, true>(smem, A, D2n, pbt * 64, B, D2n, pn * 32, D2n,
                                      C, D2n, tid);
    }
    grid_sync(P.barrier, 256u * (++sync_no));
    // ---- P3: attention, 10-row groups, static ping-pong prefetch ----
    {
      const float* qrow = (attn ? P.q2b : P.qb) + (size_t)gb * D2n;
      const float* vp = attn ? P.v2 : P.v;
      const int e0 = lane * 4, e1 = (64 + lane) * 4;
      const float4 q0 = load4_dev(qrow + e0);
      const float4 q1 = load4_dev(qrow + e1);
      const float4 v0 = *(const float4*)&vp[e0];
      const float4 v1 = *(const float4*)&vp[e1];
      float* sdst = attn ? &s2l[ab][0] : &s1l[ab][0];
      float4 Ra0[10], Ra1[10], Rb0[10], Rb1[10];
      auto ldg = [&](int jb, float4 (&R0)[10], float4 (&R1)[10]) {
#pragma unroll
        for (int jj = 0; jj < 10; ++jj) {
          if (attn == 0) {
            const RT1* row = P.ref1 + ((size_t)gb * Tn + jb + jj) * D2n;
            R0[jj] = load4<RT1>(row + e0); R1[jj] = load4<RT1>(row + e1);
          } else {
            const RT2* row = P.ref2 + ((size_t)gb * Tn + jb + jj) * D2n;
            R0[jj] = load4<RT2>(row + e0); R1[jj] = load4<RT2>(row + e1);
          }
        }
      };
      auto cmp = [&](int jb, const float4 (&R0)[10], const float4 (&R1)[10]) {
#pragma unroll
        for (int jj = 0; jj < 10; ++jj) {
          const float4 r0 = R0[jj], r1 = R1[jj];
          float a = 0.f;
          a = fmaf(fast_tanhf(r0.x + q0.x), v0.x, a);
          a = fmaf(fast_tanhf(r0.y + q0.y), v0.y, a);
          a = fmaf(fast_tanhf(r0.z + q0.z), v0.z, a);
          a = fmaf(fast_tanhf(r0.w + q0.w), v0.w, a);
          a = fmaf(fast_tanhf(r1.x + q1.x), v1.x, a);
          a = fmaf(fast_tanhf(r1.y + q1.y), v1.y, a);
          a = fmaf(fast_tanhf(r1.z + q1.z), v1.z, a);
          a = fmaf(fast_tanhf(r1.w + q1.w), v1.w, a);
#pragma unroll
          for (int off = 32; off > 0; off >>= 1) a += __shfl_xor(a, off, 64);
          if (lane == 0) sdst[jb + jj] = a;
        }
      };
      ldg(0, Ra0, Ra1);
      for (int g = 0; g < 10; g += 2) {
        if (g + 1 < 10) ldg((g + 1) * 10, Rb0, Rb1);
        cmp(g * 10, Ra0, Ra1);
        if (g + 2 < 10) ldg((g + 2) * 10, Ra0, Ra1);
        if (g + 1 < 10) cmp((g + 1) * 10, Rb0, Rb1);
      }
    }
    __syncthreads();
    // ---- P4: both owned b's in parallel on half-blocks ----
    {
      float* xnextbuf = P.xb + (size_t)((t + 1) & 1) * (Bn * D2n);
      const int b = bid * 2 + half;
      float* rf = &redf[half][0];
      int*   ri = &redi[half][0];
      const float uval = (htid < Tn) ? s2l[half][htid] : -INFINITY;
      const float owval = (htid < Tn) ? (s1l[half][htid] - PENf * playedl[half][htid])
                                      : -INFINITY;
      rf[htid] = uval; __syncthreads();
      for (int s = 64; s > 0; s >>= 1) {
        if (htid < s) rf[htid] = fmaxf(rf[htid], rf[htid + s]);
        __syncthreads();
      }
      const float umax = rf[0]; __syncthreads();
      const float e = (htid < Tn) ? __expf(uval - umax) : 0.f;
      rf[htid] = e; __syncthreads();
      for (int s = 64; s > 0; s >>= 1) {
        if (htid < s) rf[htid] += rf[htid + s];
        __syncthreads();
      }
      const float usum = rf[0]; __syncthreads();
      if (htid < Tn) awl[half][htid] = e / usum;
      rf[htid] = owval; ri[htid] = (htid < Tn) ? htid : 0x7fffffff; __syncthreads();
      for (int s = 64; s > 0; s >>= 1) {
        if (htid < s) {
          const float ov = rf[htid + s]; const int oi = ri[htid + s];
          if (ov > rf[htid] || (ov == rf[htid] && oi < ri[htid])) {
            rf[htid] = ov; ri[htid] = oi;
          }
        }
        __syncthreads();
      }
      const float omax = rf[0]; const int sel = ri[0]; __syncthreads();
      const float eo = (htid < Tn) ? __expf(owval - omax) : 0.f;
      rf[htid] = eo; __syncthreads();
      for (int s = 64; s > 0; s >>= 1) {
        if (htid < s) rf[htid] += rf[htid + s];
        __syncthreads();
      }
      if (htid == 0) {
        const float lse = omax + __logf(rf[0]);
        const int tgt = P.test_roads[b * Tn + t];
        const float owt = s1l[half][tgt] - PENf * playedl[half][tgt];
        lossl[half] += lse - owt;
        playedl[half][sel] += 1.f;
      }
      __syncthreads();
      // x_new: per-thread float4 over 4 cols, 10-row groups, static ping-pong
      const ET* Eb = P.Enc + (size_t)b * Tn * D2n;
      float* xn = xnextbuf + (size_t)b * D2n;
      const int k4 = htid * 4;            // 128 threads * 4 = 512 cols
      float4 Ea[10], Eb2[10];
      auto lde = [&](int jb, float4 (&E)[10]) {
#pragma unroll
        for (int jj = 0; jj < 10; ++jj)
          E[jj] = load4<ET>(Eb + (size_t)(jb + jj) * D2n + k4);
      };
      float4 a4 = {0.f, 0.f, 0.f, 0.f};
      auto ac4 = [&](int jb, const float4 (&E)[10]) {
#pragma unroll
        for (int jj = 0; jj < 10; ++jj) {
          const float w = awl[half][jb + jj];
          a4.x = fmaf(w, E[jj].x, a4.x);
          a4.y = fmaf(w, E[jj].y, a4.y);
          a4.z = fmaf(w, E[jj].z, a4.z);
          a4.w = fmaf(w, E[jj].w, a4.w);
        }
      };
      lde(0, Ea);
      for (int g = 0; g < 10; g += 2) {
        if (g + 1 < 10) lde((g + 1) * 10, Eb2);
        ac4(g * 10, Ea);
        if (g + 2 < 10) lde((g + 2) * 10, Ea);
        if (g + 1 < 10) ac4((g + 1) * 10, Eb2);
      }
      store4_dev(&xn[k4], a4);
    }
    grid_sync(P.barrier, 256u * (++sync_no));
  }
  if (tid == 0) {
    P.loss[bid * 2]     = lossl[0];
    P.loss[bid * 2 + 1] = lossl[1];
  }
}

// ---------------------------------------------------------------------------
template<typename ET, typename RT1, typename RT2>
static void run_all(void* const* d_in, void* d_out, char* ws, hipStream_t stream) {
  const float* inputs     = (const float*)d_in[0];
  const int*   test_roads = (const int*)d_in[1];
  const float* W_embed    = (const float*)d_in[2];
  const float* enc_Wih_f  = (const float*)d_in[3];
  const float* enc_Whh_f  = (const float*)d_in[4];
  const float* enc_b_f    = (const float*)d_in[5];
  const float* enc_Wih_b  = (const float*)d_in[6];
  const float* enc_Whh_b  = (const float*)d_in[7];
  const float* enc_b_b    = (const float*)d_in[8];
  const float* dec_Wih_f  = (const float*)d_in[9];
  const float* dec_Whh_f  = (const float*)d_in[10];
  const float* dec_b_f    = (const float*)d_in[11];
  const float* dec_Wih_b  = (const float*)d_in[12];
  const float* dec_Whh_b  = (const float*)d_in[13];
  const float* dec_b_b    = (const float*)d_in[14];
  const float* W_ref      = (const float*)d_in[15];
  const float* W_q        = (const float*)d_in[16];
  const float* v          = (const float*)d_in[17];
  const float* W_ref2     = (const float*)d_in[18];
  const float* W_q2       = (const float*)d_in[19];
  const float* v2         = (const float*)d_in[20];

  char* p0 = ws;
  ET*  Enc  = (ET*)p0;  p0 += BIGN * sizeof(ET);
  RT1* ref1 = (RT1*)p0; p0 += BIGN * sizeof(RT1);
  RT2* ref2 = (RT2*)p0; p0 += BIGN * sizeof(RT2);
  unsigned* barrier = (unsigned*)p0;                   // 256 B reserved
  float* xb      = (float*)(p0 + 256);                 // 2 * 512*512
  float* dec_out = xb + 2 * Bn * D2n;                  // 2 * 512*512
  float* hbuf    = dec_out + 2 * Bn * D2n;             // 2 * 2 * 512*256
  float* c_dec   = hbuf + 4 * Bn * Hn;                 // 2 * 512*256
  float* qb      = c_dec + 2 * Bn * Hn;
  float* q2b     = qb + Bn * D2n;
  float* weff_f  = q2b + Bn * D2n;
  float* weff_b  = weff_f + G4n * 2;

  hipMemsetAsync(ref1, 0, BIGN * (sizeof(RT1) + sizeof(RT2)), stream);
  hipMemsetAsync(barrier, 0, 256 + (size_t)Bn * D2n * 4, stream);

  weff_kernel<<<G4n / 256, 256, 0, stream>>>(enc_Wih_f, enc_Wih_b, W_embed,
                                             weff_f, weff_b);

  EncP<ET, RT1, RT2> ep = { inputs, enc_Whh_f, enc_Whh_b, enc_b_f, enc_b_b,
                            weff_f, weff_b, W_ref, W_ref2,
                            hbuf, c_dec, dec_out, Enc, ref1, ref2, barrier };
  enc_coop<ET, RT1, RT2><<<256, 256, 0, stream>>>(ep);

  DecP<ET, RT1, RT2> dp = { test_roads,
                            dec_Wih_f, dec_Whh_f, dec_b_f,
                            dec_Wih_b, dec_Whh_b, dec_b_b,
                            W_q, W_q2, v, v2,
                            Enc, ref1, ref2,
                            dec_out, xb, qb, q2b, c_dec,
                            (float*)d_out, barrier + 1 };
  dec_coop<ET, RT1, RT2><<<256, 256, 0, stream>>>(dp);
}

// ---------------------------------------------------------------------------
extern "C" void kernel_launch(void* const* d_in, const int* in_sizes, int n_in,
                              void* d_out, int out_size, void* d_ws, size_t ws_size,
                              hipStream_t stream) {
  (void)in_sizes; (void)n_in; (void)out_size;
  char* ws = (char*)d_ws;
  const size_t szA = 3 * BIGN * 4 + SMALL_BYTES;               // all f32
  const size_t szB = 2 * BIGN * 4 + BIGN * 2 + SMALL_BYTES;    // Enc f16
  const size_t szC = BIGN * 4 + 2 * BIGN * 2 + SMALL_BYTES;    // + ref2 f16
  if (ws_size >= szA)      run_all<float,  float,  float >(d_in, d_out, ws, stream);
  else if (ws_size >= szB) run_all<__half, float,  float >(d_in, d_out, ws, stream);
  else if (ws_size >= szC) run_all<__half, float,  __half>(d_in, d_out, ws, stream);
  else                     run_all<__half, __half, __half>(d_in, d_out, ws, stream);
}

// Round 12
// 17762.836 us; speedup vs baseline: 1.1927x; 1.0889x over previous
//
#include <hip/hip_runtime.h>
#include <hip/hip_fp16.h>
#include <math.h>

namespace {
constexpr int Bn  = 512;
constexpr int Tn  = 100;
constexpr int Hn  = 256;
constexpr int En  = 256;
constexpr int D2n = 512;
constexpr int G4n = 1024;
constexpr float PENf = 1e6f;
constexpr size_t BIGN = (size_t)Bn * Tn * D2n;   // 26,214,400 elements
constexpr size_t SMALL_BYTES =
    ((size_t)2 * Bn * G4n + 5 * Bn * D2n + 3 * Bn * Tn + 4 * Bn * Hn + 4 * G4n) * 4;
constexpr int FLAG_STRIDE = 32;                  // 128 B per flag line
constexpr size_t BAR_UINTS = 2 * (256 * FLAG_STRIDE + 32);
}

using short8  = __attribute__((ext_vector_type(8))) short;
using floatx4 = __attribute__((ext_vector_type(4))) float;

// ---- type conversion helpers ----------------------------------------------
template<typename T> __device__ __forceinline__ float cvt_to_f(T x);
template<> __device__ __forceinline__ float cvt_to_f<float>(float x) { return x; }
template<> __device__ __forceinline__ float cvt_to_f<__half>(__half x) {
  return __half2float(x);
}
template<typename T> __device__ __forceinline__ T cvt_from_f(float x);
template<> __device__ __forceinline__ float cvt_from_f<float>(float x) { return x; }
template<> __device__ __forceinline__ __half cvt_from_f<__half>(float x) {
  return __float2half(x);
}
__device__ __forceinline__ float h2f_bits(unsigned short b) {
  __half_raw r; r.x = b; return __half2float(__half(r));
}
template<typename T> __device__ __forceinline__ float4 load4(const T* p);
template<> __device__ __forceinline__ float4 load4<float>(const float* p) {
  return *(const float4*)p;
}
template<> __device__ __forceinline__ float4 load4<__half>(const __half* p) {
  const ushort4 u = *(const ushort4*)p;
  float4 r;
  r.x = h2f_bits(u.x); r.y = h2f_bits(u.y);
  r.z = h2f_bits(u.z); r.w = h2f_bits(u.w);
  return r;
}
__device__ __forceinline__ float sigmoidf(float x) {
  return 1.0f / (1.0f + expf(-x));
}
__device__ __forceinline__ float fast_tanhf(float x) {
  return 1.0f - 2.0f / (__expf(2.0f * x) + 1.0f);
}

// ---- device-scope (sc1) coherent accessors for DYNAMIC buffers ------------
__device__ __forceinline__ float loadf_dev(const float* p) {
  return __uint_as_float(__hip_atomic_load((const unsigned*)p, __ATOMIC_RELAXED,
                                           __HIP_MEMORY_SCOPE_AGENT));
}
__device__ __forceinline__ void storef_dev(float* p, float v) {
  __hip_atomic_store((unsigned*)p, __float_as_uint(v), __ATOMIC_RELAXED,
                     __HIP_MEMORY_SCOPE_AGENT);
}
__device__ __forceinline__ float4 load4_dev(const float* p) {
  const unsigned long long a = __hip_atomic_load((const unsigned long long*)p,
      __ATOMIC_RELAXED, __HIP_MEMORY_SCOPE_AGENT);
  const unsigned long long b = __hip_atomic_load((const unsigned long long*)p + 1,
      __ATOMIC_RELAXED, __HIP_MEMORY_SCOPE_AGENT);
  float4 r;
  r.x = __uint_as_float((unsigned)a);  r.y = __uint_as_float((unsigned)(a >> 32));
  r.z = __uint_as_float((unsigned)b);  r.w = __uint_as_float((unsigned)(b >> 32));
  return r;
}
__device__ __forceinline__ void store4_dev(float* p, const float4 v) {
  const unsigned long long a = (unsigned long long)__float_as_uint(v.x) |
                               ((unsigned long long)__float_as_uint(v.y) << 32);
  const unsigned long long b = (unsigned long long)__float_as_uint(v.z) |
                               ((unsigned long long)__float_as_uint(v.w) << 32);
  __hip_atomic_store((unsigned long long*)p, a, __ATOMIC_RELAXED,
                     __HIP_MEMORY_SCOPE_AGENT);
  __hip_atomic_store((unsigned long long*)p + 1, b, __ATOMIC_RELAXED,
                     __HIP_MEMORY_SCOPE_AGENT);
}
template<typename CT> __device__ __forceinline__ CT load_dev(const CT* p);
template<> __device__ __forceinline__ float load_dev<float>(const float* p) {
  return loadf_dev(p);
}
template<> __device__ __forceinline__ __half load_dev<__half>(const __half* p) {
  unsigned short u = __hip_atomic_load((const unsigned short*)p, __ATOMIC_RELAXED,
                                       __HIP_MEMORY_SCOPE_AGENT);
  __half_raw r; r.x = u; return (__half)r;
}
template<typename CT> __device__ __forceinline__ void store_dev(CT* p, CT v);
template<> __device__ __forceinline__ void store_dev<float>(float* p, float v) {
  storef_dev(p, v);
}
template<> __device__ __forceinline__ void store_dev<__half>(__half* p, __half v) {
  __half_raw r = *reinterpret_cast<__half_raw*>(&v);
  __hip_atomic_store((unsigned short*)p, r.x, __ATOMIC_RELAXED,
                     __HIP_MEMORY_SCOPE_AGENT);
}

// fp32 -> (hi bf16 truncate, lo bf16 rne of residual)
__device__ __forceinline__ void split2(float x, short& h, short& l) {
  const unsigned u  = __float_as_uint(x);
  const unsigned hu = u & 0xffff0000u;
  h = (short)(hu >> 16);
  const float r = x - __uint_as_float(hu);
  l = (short)((__float_as_uint(r) + 0x8000u) >> 16);
}
__device__ __forceinline__ void store4split(const float4 v, short* hp, short* lp) {
  short h0, h1, h2, h3, l0, l1, l2, l3;
  split2(v.x, h0, l0); split2(v.y, h1, l1);
  split2(v.z, h2, l2); split2(v.w, h3, l3);
  *(short4*)hp = make_short4(h0, h1, h2, h3);
  *(short4*)lp = make_short4(l0, l1, l2, l3);
}

// ---- distributed-arrival grid barrier (256 blocks, 1/CU) ------------------
// Arrival: each block STOREs its step number to its own padded flag line (no
// RMW, no shared-line contention — the serialized 256-way fetch_add on one
// line was the invariant ~50 µs across rounds 5-11). Block 0's 256 threads
// sweep all flags (one vector load per wave covers 64 flags), then thread 0
// publishes the epoch on a separate release line; others poll it read-only.
// s_waitcnt(0) before arrival orders each block's sc1 data stores (at LLC)
// before its flag store; all cross-block data is sc1 on both sides, so no
// cache-maintenance fences are needed anywhere.
__device__ __forceinline__ void grid_sync(unsigned* flags, unsigned* release,
                                          unsigned no) {
  __builtin_amdgcn_s_waitcnt(0);
  __syncthreads();
  if (blockIdx.x == 0) {
    const int tid = threadIdx.x;
    if (tid > 0) {
      while (__hip_atomic_load(&flags[tid * FLAG_STRIDE], __ATOMIC_RELAXED,
                               __HIP_MEMORY_SCOPE_AGENT) < no)
        __builtin_amdgcn_s_sleep(1);
    }
    __syncthreads();
    if (tid == 0)
      __hip_atomic_store(release, no, __ATOMIC_RELAXED, __HIP_MEMORY_SCOPE_AGENT);
  } else {
    if (threadIdx.x == 0) {
      __hip_atomic_store(&flags[blockIdx.x * FLAG_STRIDE], no, __ATOMIC_RELAXED,
                         __HIP_MEMORY_SCOPE_AGENT);
      while (__hip_atomic_load(release, __ATOMIC_RELAXED,
                               __HIP_MEMORY_SCOPE_AGENT) < no)
        __builtin_amdgcn_s_sleep(2);
    }
    __syncthreads();
  }
}

// ---------------------------------------------------------------------------
// Pipelined 64xN GEMM: C (+)= A[64,K]*B[N,K]^T, split-bf16 MFMA (hh,hl,lh).
// A is DYNAMIC (sc1 loads); B is static (plain cached). CSC: C via sc1.
// ---------------------------------------------------------------------------
template<typename CT, bool ACC, int NT, bool CSC>
__device__ __forceinline__ void gemm64v2(short* smem,
    const float* A, int lda, int m0,
    const float* B, int ldb, int n0, int K,
    CT* Cbase, size_t crstride, int tid) {
  constexpr int BPL  = NT * 128;             // B kgroup stride (shorts)
  constexpr int BSZ  = NT * 512;             // B plane size (shorts)
  constexpr int BUFS = 4096 + 2 * BSZ;       // shorts per LDS buffer
  const int lane = tid & 63, wave = tid >> 6, qm = lane & 15, quad = lane >> 4;
  const int ra = tid >> 3, c4 = tid & 7, j0 = (c4 & 1) * 4, gq = c4 >> 1;
  const int a0 = gq * 512 + ra * 8 + j0;
  const int a1 = gq * 512 + (ra + 32) * 8 + j0;
  const int b0 = gq * BPL + ra * 8 + j0;
  const int b1 = gq * BPL + (ra + 32) * 8 + j0;
  const int CN = K >> 5;

  floatx4 acc[NT];
#pragma unroll
  for (int nt = 0; nt < NT; ++nt) acc[nt] = (floatx4){0.f, 0.f, 0.f, 0.f};

  float4 Aa0, Aa1, Ba0, Ba1, Ab0, Ab1, Bb0, Bb1;
  auto ld = [&](int c, float4& x0, float4& x1, float4& y0, float4& y1) {
    const int k0 = c * 32 + c4 * 4;
    x0 = load4_dev(A + (size_t)(m0 + ra) * lda + k0);
    x1 = load4_dev(A + (size_t)(m0 + ra + 32) * lda + k0);
    y0 = *(const float4*)(B + (size_t)(n0 + ra) * ldb + k0);
    if (NT == 4)
      y1 = *(const float4*)(B + (size_t)(n0 + ra + 32) * ldb + k0);
  };
  auto st = [&](short* bp, const float4& x0, const float4& x1,
                const float4& y0, const float4& y1) {
    store4split(x0, bp + a0, bp + 2048 + a0);
    store4split(x1, bp + a1, bp + 2048 + a1);
    store4split(y0, bp + 4096 + b0, bp + 4096 + BSZ + b0);
    if (NT == 4) store4split(y1, bp + 4096 + b1, bp + 4096 + BSZ + b1);
  };
  auto mm = [&](const short* bp) {
    const int abase = quad * 512 + (wave * 16 + qm) * 8;
    const short8 ah = *(const short8*)&bp[abase];
    const short8 al = *(const short8*)&bp[2048 + abase];
#pragma unroll
    for (int nt = 0; nt < NT; ++nt) {
      const int bb = quad * BPL + (nt * 16 + qm) * 8;
      const short8 bh = *(const short8*)&bp[4096 + bb];
      const short8 bl = *(const short8*)&bp[4096 + BSZ + bb];
      acc[nt] = __builtin_amdgcn_mfma_f32_16x16x32_bf16(ah, bh, acc[nt], 0, 0, 0);
      acc[nt] = __builtin_amdgcn_mfma_f32_16x16x32_bf16(ah, bl, acc[nt], 0, 0, 0);
      acc[nt] = __builtin_amdgcn_mfma_f32_16x16x32_bf16(al, bh, acc[nt], 0, 0, 0);
    }
  };

  ld(0, Aa0, Aa1, Ba0, Ba1);
  if (CN > 1) ld(1, Ab0, Ab1, Bb0, Bb1);
  st(smem, Aa0, Aa1, Ba0, Ba1);
  __syncthreads();
  for (int c = 0; c < CN; c += 2) {
    if (c + 2 < CN) ld(c + 2, Aa0, Aa1, Ba0, Ba1);
    mm(smem);
    if (c + 1 < CN) st(smem + BUFS, Ab0, Ab1, Bb0, Bb1);
    __syncthreads();
    if (c + 1 < CN) {
      if (c + 3 < CN) ld(c + 3, Ab0, Ab1, Bb0, Bb1);
      mm(smem + BUFS);
      if (c + 2 < CN) st(smem, Aa0, Aa1, Ba0, Ba1);
      __syncthreads();
    }
  }

#pragma unroll
  for (int nt = 0; nt < NT; ++nt)
#pragma unroll
    for (int r2 = 0; r2 < 4; ++r2) {
      const int m = wave * 16 + quad * 4 + r2, n = nt * 16 + qm;
      CT* cp = Cbase + (size_t)m * crstride + n;
      float o = acc[nt][r2];
      if (CSC) {
        if (ACC) o += cvt_to_f<CT>(load_dev<CT>(cp));
        store_dev<CT>(cp, cvt_from_f<CT>(o));
      } else {
        if (ACC) o += cvt_to_f<CT>(*cp);
        *cp = cvt_from_f<CT>(o);
      }
    }
}

// ---------------------------------------------------------------------------
// Pipelined gate GEMM: 4 accs (i,f,g,o), out tile 64(m) x 16(h-slice)/gate.
// ---------------------------------------------------------------------------
__device__ __forceinline__ void gates_gemm_v2(floatx4 acc[4], short* smem,
    const float* A1, int lda1, const float* B1, int ldb1, int K1,
    const float* A2, int lda2, const float* B2, int ldb2, int K2,
    int m0, int hoff, int tid) {
  const int lane = tid & 63, wave = tid >> 6, qm = lane & 15, quad = lane >> 4;
  const int ra = tid >> 3, c4 = tid & 7, j0 = (c4 & 1) * 4, gq = c4 >> 1;
  const int a0 = gq * 512 + ra * 8 + j0;
  const int a1 = gq * 512 + (ra + 32) * 8 + j0;
  const int g0 = (ra >> 4) * Hn + hoff + (ra & 15);
  const int g1 = ((ra + 32) >> 4) * Hn + hoff + ((ra + 32) & 15);
  const int C1 = K1 >> 5;
  const int C2 = A2 ? (K2 >> 5) : 0;
  const int CN = C1 + C2;

  float4 Aa0, Aa1, Ba0, Ba1, Ab0, Ab1, Bb0, Bb1;
  auto ld = [&](int c, float4& x0, float4& x1, float4& y0, float4& y1) {
    const float* A; const float* B; int lda, ldb, k0;
    if (c < C1) { A = A1; B = B1; lda = lda1; ldb = ldb1; k0 = c * 32; }
    else        { A = A2; B = B2; lda = lda2; ldb = ldb2; k0 = (c - C1) * 32; }
    k0 += c4 * 4;
    x0 = load4_dev(A + (size_t)(m0 + ra) * lda + k0);
    x1 = load4_dev(A + (size_t)(m0 + ra + 32) * lda + k0);
    y0 = *(const float4*)(B + (size_t)g0 * ldb + k0);
    y1 = *(const float4*)(B + (size_t)g1 * ldb + k0);
  };
  auto st2 = [&](short* bp, const float4& x0, const float4& x1,
                 const float4& y0, const float4& y1) {
    store4split(x0, bp + a0, bp + 2048 + a0);
    store4split(x1, bp + a1, bp + 2048 + a1);
    store4split(y0, bp + 4096 + a0, bp + 6144 + a0);
    store4split(y1, bp + 4096 + a1, bp + 6144 + a1);
  };
  auto mm = [&](const short* bp) {
    const int abase = quad * 512 + (wave * 16 + qm) * 8;
    const short8 ah = *(const short8*)&bp[abase];
    const short8 al = *(const short8*)&bp[2048 + abase];
#pragma unroll
    for (int gg = 0; gg < 4; ++gg) {
      const int bb = quad * 512 + (gg * 16 + qm) * 8;
      const short8 bh = *(const short8*)&bp[4096 + bb];
      const short8 bl = *(const short8*)&bp[6144 + bb];
      acc[gg] = __builtin_amdgcn_mfma_f32_16x16x32_bf16(ah, bh, acc[gg], 0, 0, 0);
      acc[gg] = __builtin_amdgcn_mfma_f32_16x16x32_bf16(ah, bl, acc[gg], 0, 0, 0);
      acc[gg] = __builtin_amdgcn_mfma_f32_16x16x32_bf16(al, bh, acc[gg], 0, 0, 0);
    }
  };

  if (CN <= 0) return;
  ld(0, Aa0, Aa1, Ba0, Ba1);
  if (CN > 1) ld(1, Ab0, Ab1, Bb0, Bb1);
  st2(smem, Aa0, Aa1, Ba0, Ba1);
  __syncthreads();
  for (int c = 0; c < CN; c += 2) {
    if (c + 2 < CN) ld(c + 2, Aa0, Aa1, Ba0, Ba1);
    mm(smem);
    if (c + 1 < CN) st2(smem + 8192, Ab0, Ab1, Bb0, Bb1);
    __syncthreads();
    if (c + 1 < CN) {
      if (c + 3 < CN) ld(c + 3, Ab0, Ab1, Bb0, Bb1);
      mm(smem + 8192);
      if (c + 2 < CN) st2(smem, Aa0, Aa1, Ba0, Ba1);
      __syncthreads();
    }
  }
}

// ---------------------------------------------------------------------------
__global__ void weff_kernel(const float* Wih_f, const float* Wih_b,
                            const float* W_embed, float* weff_f, float* weff_b) {
  const int gidx = blockIdx.x * 256 + threadIdx.x;
  if (gidx >= G4n) return;
  float f0 = 0.f, f1 = 0.f, b0 = 0.f, b1 = 0.f;
  for (int e = 0; e < En; ++e) {
    const float w0 = W_embed[e * 2 + 0];
    const float w1 = W_embed[e * 2 + 1];
    const float wf = Wih_f[gidx * En + e];
    const float wb = Wih_b[gidx * En + e];
    f0 = fmaf(wf, w0, f0); f1 = fmaf(wf, w1, f1);
    b0 = fmaf(wb, w0, b0); b1 = fmaf(wb, w1, b1);
  }
  weff_f[gidx * 2 + 0] = f0; weff_f[gidx * 2 + 1] = f1;
  weff_b[gidx * 2 + 0] = b0; weff_b[gidx * 2 + 1] = b1;
}

// ---------------------------------------------------------------------------
// Persistent encoder: 100 steps, 1 grid-sync/step. 256 blocks.
// ---------------------------------------------------------------------------
template<typename ET, typename RT1, typename RT2>
struct EncP {
  const float* inputs;
  const float* Whh_f; const float* Whh_b;
  const float* b_f; const float* b_b;
  const float* weff_f; const float* weff_b;
  const float* W_ref; const float* W_ref2;
  float* hbuf;       // [2 parity][2 dir][512*256]  (dynamic, sc1)
  float* c_dec;      // [2 dir][512*256]            (kernel-boundary)
  float* dec_out0;   // [512*512]                   (kernel-boundary)
  ET* Enc; RT1* ref1; RT2* ref2;
  unsigned* flags; unsigned* release;
};

template<typename ET, typename RT1, typename RT2>
__global__ __launch_bounds__(256, 1) void enc_coop(EncP<ET, RT1, RT2> P) {
  __shared__ __align__(16) short smem[16384];
  const int bid = blockIdx.x, tid = threadIdx.x;
  const int dir = bid >> 7, btile = (bid >> 4) & 7, hs = bid & 15;
  const int r_ref = (bid >> 7) & 1, r_dir = (bid >> 6) & 1;
  const int r_bt = (bid >> 3) & 7, r_ns = bid & 7;
  const int lane = tid & 63, wave = tid >> 6, qm = lane & 15, quad = lane >> 4;
  const int hcol = hs * 16 + qm;
  const float* Whh  = dir ? P.Whh_b : P.Whh_f;
  const float* bias = dir ? P.b_b : P.b_f;
  const float* weff = dir ? P.weff_b : P.weff_f;
  float c_reg[4] = {0.f, 0.f, 0.f, 0.f};
  float h_reg[4] = {0.f, 0.f, 0.f, 0.f};
  unsigned sync_no = 0;

  auto ref_job = [&](const float* hpar, int pos) {
    const float* hsrc = hpar + (size_t)r_dir * (Bn * Hn);
    if (r_ref == 0)
      gemm64v2<RT1, true, 4, true>(smem, hsrc, Hn, r_bt * 64,
                             P.W_ref + r_dir * Hn, D2n, r_ns * 64, Hn,
                             P.ref1 + (size_t)(r_bt * 64) * Tn * D2n + (size_t)pos * D2n + r_ns * 64,
                             (size_t)Tn * D2n, tid);
    else
      gemm64v2<RT2, true, 4, true>(smem, hsrc, Hn, r_bt * 64,
                             P.W_ref2 + r_dir * Hn, D2n, r_ns * 64, Hn,
                             P.ref2 + (size_t)(r_bt * 64) * Tn * D2n + (size_t)pos * D2n + r_ns * 64,
                             (size_t)Tn * D2n, tid);
  };

  for (int t = 0; t < Tn; ++t) {
    const float* hprev = P.hbuf + (size_t)((t - 1) & 1) * (2 * Bn * Hn);
    if (t > 0) ref_job(hprev, r_dir ? (Tn - t) : (t - 1));
    floatx4 acc[4];
#pragma unroll
    for (int gg = 0; gg < 4; ++gg) acc[gg] = (floatx4){0.f, 0.f, 0.f, 0.f};
    if (t > 0)
      gates_gemm_v2(acc, smem, hprev + (size_t)dir * (Bn * Hn), Hn, Whh, Hn, Hn,
                    nullptr, 0, nullptr, 0, 0, btile * 64, hs * 16, tid);
    const int tcur = dir ? (Tn - 1 - t) : t;
    float xa[4], xb2[4];
#pragma unroll
    for (int r2 = 0; r2 < 4; ++r2) {
      const int m = btile * 64 + wave * 16 + quad * 4 + r2;
      xa[r2]  = P.inputs[(size_t)m * (Tn * 2) + tcur * 2 + 0];
      xb2[r2] = P.inputs[(size_t)m * (Tn * 2) + tcur * 2 + 1];
    }
    float gv[4][4];
#pragma unroll
    for (int gg = 0; gg < 4; ++gg) {
      const int grow = gg * Hn + hcol;
      const float bn = bias[grow];
      const float w20 = weff[grow * 2], w21 = weff[grow * 2 + 1];
#pragma unroll
      for (int r2 = 0; r2 < 4; ++r2) {
        float o = acc[gg][r2] + bn;
        o = fmaf(xa[r2], w20, fmaf(xb2[r2], w21, o));
        gv[gg][r2] = o;
      }
    }
    float* hdst = P.hbuf + (size_t)(t & 1) * (2 * Bn * Hn) + (size_t)dir * (Bn * Hn);
    const int tt = dir ? (Tn - 1 - t) : t;
#pragma unroll
    for (int r2 = 0; r2 < 4; ++r2) {
      const float cn = sigmoidf(gv[1][r2]) * c_reg[r2] +
                       sigmoidf(gv[0][r2]) * tanhf(gv[2][r2]);
      c_reg[r2] = cn;
      const float hn = sigmoidf(gv[3][r2]) * tanhf(cn);
      h_reg[r2] = hn;
      const int m = btile * 64 + wave * 16 + quad * 4 + r2;
      storef_dev(&hdst[(size_t)m * Hn + hcol], hn);
      store_dev<ET>(&P.Enc[(size_t)m * Tn * D2n + (size_t)tt * D2n + dir * Hn + hcol],
                    cvt_from_f<ET>(hn));
    }
    grid_sync(P.flags, P.release, ++sync_no);
  }
  ref_job(P.hbuf + (size_t)1 * (2 * Bn * Hn), r_dir ? 0 : (Tn - 1));
#pragma unroll
  for (int r2 = 0; r2 < 4; ++r2) {
    const int m = btile * 64 + wave * 16 + quad * 4 + r2;
    P.dec_out0[(size_t)m * D2n + dir * Hn + hcol] = h_reg[r2];
    P.c_dec[((size_t)dir * Bn + m) * Hn + hcol] = c_reg[r2];
  }
}

// ---------------------------------------------------------------------------
// Persistent decoder: 100 steps, 3 grid-syncs/step. 256 blocks.
// ---------------------------------------------------------------------------
template<typename ET, typename RT1, typename RT2>
struct DecP {
  const int* test_roads;
  const float* Wih_f; const float* Whh_f; const float* b_f;
  const float* Wih_b; const float* Whh_b; const float* b_b;
  const float* W_q; const float* W_q2; const float* v; const float* v2;
  const ET* Enc; const RT1* ref1; const RT2* ref2;
  float* dec_out;    // [2][512*512] (dynamic, sc1)
  float* xb;         // [2][512*512] (dynamic, sc1)
  float* qb; float* q2b;            // (dynamic, sc1)
  const float* c_init;  // [2][512*256] (kernel-boundary)
  float* loss;       // d_out [512]
  unsigned* flags; unsigned* release;
};

template<typename ET, typename RT1, typename RT2>
__global__ __launch_bounds__(256, 1) void dec_coop(DecP<ET, RT1, RT2> P) {
  __shared__ __align__(16) short smem[16384];
  __shared__ float s1l[2][104], s2l[2][104];
  __shared__ float awl[2][104];
  __shared__ float redf[2][128];
  __shared__ int   redi[2][128];
  __shared__ float playedl[2][104];
  __shared__ float lossl[2];
  const int bid = blockIdx.x, tid = threadIdx.x;
  const int dir = bid >> 7, btile = (bid >> 4) & 7, hs = bid & 15;
  const int lane = tid & 63, wave = tid >> 6, qm = lane & 15, quad = lane >> 4;
  const int hcol = hs * 16 + qm;
  const float* Wih  = dir ? P.Wih_b : P.Wih_f;
  const float* Whh  = dir ? P.Whh_b : P.Whh_f;
  const float* bias = dir ? P.b_b : P.b_f;
  float c_reg[4];
#pragma unroll
  for (int r2 = 0; r2 < 4; ++r2) {
    const int m = btile * 64 + wave * 16 + quad * 4 + r2;
    c_reg[r2] = P.c_init[((size_t)dir * Bn + m) * Hn + hcol];
  }
  if (tid < Tn) { playedl[0][tid] = 0.f; playedl[1][tid] = 0.f; }
  if (tid < 2) lossl[tid] = 0.f;
  // P2: 256 jobs of 64x32
  const int proj = bid >> 7, pbt = (bid >> 4) & 7, pn = bid & 15;
  // P3 mapping: wave -> (local b, attn)
  const int ab = wave >> 1, attn = wave & 1;
  const int gb = bid * 2 + ab;
  const int half = tid >> 7, htid = tid & 127;
  unsigned sync_no = 0;
  __syncthreads();

  for (int t = 0; t < Tn; ++t) {
    const float* xc  = P.xb + (size_t)(t & 1) * (Bn * D2n);
    const float* dcur = P.dec_out + (size_t)(t & 1) * (Bn * D2n);
    float* dnext = P.dec_out + (size_t)((t + 1) & 1) * (Bn * D2n);
    // ---- P1: cell gates + LSTM ----
    floatx4 acc[4];
#pragma unroll
    for (int gg = 0; gg < 4; ++gg) acc[gg] = (floatx4){0.f, 0.f, 0.f, 0.f};
    gates_gemm_v2(acc, smem, xc, D2n, Wih, D2n, D2n,
                  dcur + dir * Hn, D2n, Whh, Hn, Hn, btile * 64, hs * 16, tid);
#pragma unroll
    for (int gg = 0; gg < 4; ++gg) {
      const float bn = bias[gg * Hn + hcol];
#pragma unroll
      for (int r2 = 0; r2 < 4; ++r2) acc[gg][r2] += bn;
    }
#pragma unroll
    for (int r2 = 0; r2 < 4; ++r2) {
      const float cn = sigmoidf(acc[1][r2]) * c_reg[r2] +
                       sigmoidf(acc[0][r2]) * tanhf(acc[2][r2]);
      c_reg[r2] = cn;
      const float hn = sigmoidf(acc[3][r2]) * tanhf(cn);
      const int m = btile * 64 + wave * 16 + quad * 4 + r2;
      storef_dev(&dnext[(size_t)m * D2n + dir * Hn + hcol], hn);
    }
    grid_sync(P.flags, P.release, ++sync_no);
    // ---- P2: q projections (256 jobs, 64x32 tiles) ----
    {
      const float* A = proj ? xc : dnext;
      const float* B = proj ? P.W_q2 : P.W_q;
      float* C = (proj ? P.q2b : P.qb) + (size_t)(pbt * 64) * D2n + pn * 32;
      gemm64v2<float, false, 2, true>(smem, A, D2n, pbt * 64, B, D2n, pn * 32, D2n,
                                      C, D2n, tid);
    }
    grid_sync(P.flags, P.release, ++sync_no);
    // ---- P3: attention, 10-row groups, static ping-pong prefetch ----
    {
      const float* qrow = (attn ? P.q2b : P.qb) + (size_t)gb * D2n;
      const float* vp = attn ? P.v2 : P.v;
      const int e0 = lane * 4, e1 = (64 + lane) * 4;
      const float4 q0 = load4_dev(qrow + e0);
      const float4 q1 = load4_dev(qrow + e1);
      const float4 v0 = *(const float4*)&vp[e0];
      const float4 v1 = *(const float4*)&vp[e1];
      float* sdst = attn ? &s2l[ab][0] : &s1l[ab][0];
      float4 Ra0[10], Ra1[10], Rb0[10], Rb1[10];
      auto ldg = [&](int jb, float4 (&R0)[10], float4 (&R1)[10]) {
#pragma unroll
        for (int jj = 0; jj < 10; ++jj) {
          if (attn == 0) {
            const RT1* row = P.ref1 + ((size_t)gb * Tn + jb + jj) * D2n;
            R0[jj] = load4<RT1>(row + e0); R1[jj] = load4<RT1>(row + e1);
          } else {
            const RT2* row = P.ref2 + ((size_t)gb * Tn + jb + jj) * D2n;
            R0[jj] = load4<RT2>(row + e0); R1[jj] = load4<RT2>(row + e1);
          }
        }
      };
      auto cmp = [&](int jb, const float4 (&R0)[10], const float4 (&R1)[10]) {
#pragma unroll
        for (int jj = 0; jj < 10; ++jj) {
          const float4 r0 = R0[jj], r1 = R1[jj];
          float a = 0.f;
          a = fmaf(fast_tanhf(r0.x + q0.x), v0.x, a);
          a = fmaf(fast_tanhf(r0.y + q0.y), v0.y, a);
          a = fmaf(fast_tanhf(r0.z + q0.z), v0.z, a);
          a = fmaf(fast_tanhf(r0.w + q0.w), v0.w, a);
          a = fmaf(fast_tanhf(r1.x + q1.x), v1.x, a);
          a = fmaf(fast_tanhf(r1.y + q1.y), v1.y, a);
          a = fmaf(fast_tanhf(r1.z + q1.z), v1.z, a);
          a = fmaf(fast_tanhf(r1.w + q1.w), v1.w, a);
#pragma unroll
          for (int off = 32; off > 0; off >>= 1) a += __shfl_xor(a, off, 64);
          if (lane == 0) sdst[jb + jj] = a;
        }
      };
      ldg(0, Ra0, Ra1);
      for (int g = 0; g < 10; g += 2) {
        if (g + 1 < 10) ldg((g + 1) * 10, Rb0, Rb1);
        cmp(g * 10, Ra0, Ra1);
        if (g + 2 < 10) ldg((g + 2) * 10, Ra0, Ra1);
        if (g + 1 < 10) cmp((g + 1) * 10, Rb0, Rb1);
      }
    }
    __syncthreads();
    // ---- P4: both owned b's in parallel on half-blocks ----
    {
      float* xnextbuf = P.xb + (size_t)((t + 1) & 1) * (Bn * D2n);
      const int b = bid * 2 + half;
      float* rf = &redf[half][0];
      int*   ri = &redi[half][0];
      const float uval = (htid < Tn) ? s2l[half][htid] : -INFINITY;
      const float owval = (htid < Tn) ? (s1l[half][htid] - PENf * playedl[half][htid])
                                      : -INFINITY;
      rf[htid] = uval; __syncthreads();
      for (int s = 64; s > 0; s >>= 1) {
        if (htid < s) rf[htid] = fmaxf(rf[htid], rf[htid + s]);
        __syncthreads();
      }
      const float umax = rf[0]; __syncthreads();
      const float e = (htid < Tn) ? __expf(uval - umax) : 0.f;
      rf[htid] = e; __syncthreads();
      for (int s = 64; s > 0; s >>= 1) {
        if (htid < s) rf[htid] += rf[htid + s];
        __syncthreads();
      }
      const float usum = rf[0]; __syncthreads();
      if (htid < Tn) awl[half][htid] = e / usum;
      rf[htid] = owval; ri[htid] = (htid < Tn) ? htid : 0x7fffffff; __syncthreads();
      for (int s = 64; s > 0; s >>= 1) {
        if (htid < s) {
          const float ov = rf[htid + s]; const int oi = ri[htid + s];
          if (ov > rf[htid] || (ov == rf[htid] && oi < ri[htid])) {
            rf[htid] = ov; ri[htid] = oi;
          }
        }
        __syncthreads();
      }
      const float omax = rf[0]; const int sel = ri[0]; __syncthreads();
      const float eo = (htid < Tn) ? __expf(owval - omax) : 0.f;
      rf[htid] = eo; __syncthreads();
      for (int s = 64; s > 0; s >>= 1) {
        if (htid < s) rf[htid] += rf[htid + s];
        __syncthreads();
      }
      if (htid == 0) {
        const float lse = omax + __logf(rf[0]);
        const int tgt = P.test_roads[b * Tn + t];
        const float owt = s1l[half][tgt] - PENf * playedl[half][tgt];
        lossl[half] += lse - owt;
        playedl[half][sel] += 1.f;
      }
      __syncthreads();
      // x_new: per-thread float4 over 4 cols, 10-row groups, static ping-pong
      const ET* Eb = P.Enc + (size_t)b * Tn * D2n;
      float* xn = xnextbuf + (size_t)b * D2n;
      const int k4 = htid * 4;            // 128 threads * 4 = 512 cols
      float4 Ea[10], Eb2[10];
      auto lde = [&](int jb, float4 (&E)[10]) {
#pragma unroll
        for (int jj = 0; jj < 10; ++jj)
          E[jj] = load4<ET>(Eb + (size_t)(jb + jj) * D2n + k4);
      };
      float4 a4 = {0.f, 0.f, 0.f, 0.f};
      auto ac4 = [&](int jb, const float4 (&E)[10]) {
#pragma unroll
        for (int jj = 0; jj < 10; ++jj) {
          const float w = awl[half][jb + jj];
          a4.x = fmaf(w, E[jj].x, a4.x);
          a4.y = fmaf(w, E[jj].y, a4.y);
          a4.z = fmaf(w, E[jj].z, a4.z);
          a4.w = fmaf(w, E[jj].w, a4.w);
        }
      };
      lde(0, Ea);
      for (int g = 0; g < 10; g += 2) {
        if (g + 1 < 10) lde((g + 1) * 10, Eb2);
        ac4(g * 10, Ea);
        if (g + 2 < 10) lde((g + 2) * 10, Ea);
        if (g + 1 < 10) ac4((g + 1) * 10, Eb2);
      }
      store4_dev(&xn[k4], a4);
    }
    grid_sync(P.flags, P.release, ++sync_no);
  }
  if (tid == 0) {
    P.loss[bid * 2]     = lossl[0];
    P.loss[bid * 2 + 1] = lossl[1];
  }
}

// ---------------------------------------------------------------------------
template<typename ET, typename RT1, typename RT2>
static void run_all(void* const* d_in, void* d_out, char* ws, hipStream_t stream) {
  const float* inputs     = (const float*)d_in[0];
  const int*   test_roads = (const int*)d_in[1];
  const float* W_embed    = (const float*)d_in[2];
  const float* enc_Wih_f  = (const float*)d_in[3];
  const float* enc_Whh_f  = (const float*)d_in[4];
  const float* enc_b_f    = (const float*)d_in[5];
  const float* enc_Wih_b  = (const float*)d_in[6];
  const float* enc_Whh_b  = (const float*)d_in[7];
  const float* enc_b_b    = (const float*)d_in[8];
  const float* dec_Wih_f  = (const float*)d_in[9];
  const float* dec_Whh_f  = (const float*)d_in[10];
  const float* dec_b_f    = (const float*)d_in[11];
  const float* dec_Wih_b  = (const float*)d_in[12];
  const float* dec_Whh_b  = (const float*)d_in[13];
  const float* dec_b_b    = (const float*)d_in[14];
  const float* W_ref      = (const float*)d_in[15];
  const float* W_q        = (const float*)d_in[16];
  const float* v          = (const float*)d_in[17];
  const float* W_ref2     = (const float*)d_in[18];
  const float* W_q2       = (const float*)d_in[19];
  const float* v2         = (const float*)d_in[20];

  char* p0 = ws;
  ET*  Enc  = (ET*)p0;  p0 += BIGN * sizeof(ET);
  RT1* ref1 = (RT1*)p0; p0 += BIGN * sizeof(RT1);
  RT2* ref2 = (RT2*)p0; p0 += BIGN * sizeof(RT2);
  unsigned* flagsE = (unsigned*)p0;                 // 256 padded lines
  unsigned* relE   = flagsE + 256 * FLAG_STRIDE;
  unsigned* flagsD = relE + 32;
  unsigned* relD   = flagsD + 256 * FLAG_STRIDE;
  float* xb      = (float*)(p0 + BAR_UINTS * 4);
  float* dec_out = xb + 2 * Bn * D2n;               // 2 * 512*512
  float* hbuf    = dec_out + 2 * Bn * D2n;          // 2 * 2 * 512*256
  float* c_dec   = hbuf + 4 * Bn * Hn;              // 2 * 512*256
  float* qb      = c_dec + 2 * Bn * Hn;
  float* q2b     = qb + Bn * D2n;
  float* weff_f  = q2b + Bn * D2n;
  float* weff_b  = weff_f + G4n * 2;

  hipMemsetAsync(ref1, 0, BIGN * (sizeof(RT1) + sizeof(RT2)), stream);
  hipMemsetAsync(flagsE, 0, BAR_UINTS * 4 + (size_t)Bn * D2n * 4, stream);

  weff_kernel<<<G4n / 256, 256, 0, stream>>>(enc_Wih_f, enc_Wih_b, W_embed,
                                             weff_f, weff_b);

  EncP<ET, RT1, RT2> ep = { inputs, enc_Whh_f, enc_Whh_b, enc_b_f, enc_b_b,
                            weff_f, weff_b, W_ref, W_ref2,
                            hbuf, c_dec, dec_out, Enc, ref1, ref2,
                            flagsE, relE };
  enc_coop<ET, RT1, RT2><<<256, 256, 0, stream>>>(ep);

  DecP<ET, RT1, RT2> dp = { test_roads,
                            dec_Wih_f, dec_Whh_f, dec_b_f,
                            dec_Wih_b, dec_Whh_b, dec_b_b,
                            W_q, W_q2, v, v2,
                            Enc, ref1, ref2,
                            dec_out, xb, qb, q2b, c_dec,
                            (float*)d_out, flagsD, relD };
  dec_coop<ET, RT1, RT2><<<256, 256, 0, stream>>>(dp);
}

// ---------------------------------------------------------------------------
extern "C" void kernel_launch(void* const* d_in, const int* in_sizes, int n_in,
                              void* d_out, int out_size, void* d_ws, size_t ws_size,
                              hipStream_t stream) {
  (void)in_sizes; (void)n_in; (void)out_size;
  char* ws = (char*)d_ws;
  const size_t szA = 3 * BIGN * 4 + SMALL_BYTES;               // all f32
  const size_t szB = 2 * BIGN * 4 + BIGN * 2 + SMALL_BYTES;    // Enc f16
  const size_t szC = BIGN * 4 + 2 * BIGN * 2 + SMALL_BYTES;    // + ref2 f16
  if (ws_size >= szA)      run_all<float,  float,  float >(d_in, d_out, ws, stream);
  else if (ws_size >= szB) run_all<__half, float,  float >(d_in, d_out, ws, stream);
  else if (ws_size >= szC) run_all<__half, float,  __half>(d_in, d_out, ws, stream);
  else                     run_all<__half, __half, __half>(d_in, d_out, ws, stream);
}

// Round 13
// 13972.275 us; speedup vs baseline: 1.5163x; 1.2713x over previous
//
#include <hip/hip_runtime.h>
#include <hip/hip_fp16.h>
#include <math.h>

namespace {
constexpr int Bn  = 512;
constexpr int Tn  = 100;
constexpr int Hn  = 256;
constexpr int En  = 256;
constexpr int D2n = 512;
constexpr int G4n = 1024;
constexpr float PENf = 1e6f;
constexpr size_t BIGN = (size_t)Bn * Tn * D2n;   // 26,214,400 elements
constexpr int FLAG_STRIDE = 32;                  // 128 B per flag line
constexpr size_t BAR_UINTS = 2 * (256 * FLAG_STRIDE + 32);
}

using short8  = __attribute__((ext_vector_type(8))) short;
using floatx4 = __attribute__((ext_vector_type(4))) float;

// ---- type conversion helpers ----------------------------------------------
template<typename T> __device__ __forceinline__ float cvt_to_f(T x);
template<> __device__ __forceinline__ float cvt_to_f<float>(float x) { return x; }
template<> __device__ __forceinline__ float cvt_to_f<__half>(__half x) {
  return __half2float(x);
}
template<typename T> __device__ __forceinline__ T cvt_from_f(float x);
template<> __device__ __forceinline__ float cvt_from_f<float>(float x) { return x; }
template<> __device__ __forceinline__ __half cvt_from_f<__half>(float x) {
  return __float2half(x);
}
__device__ __forceinline__ float h2f_bits(unsigned short b) {
  __half_raw r; r.x = b; return __half2float(__half(r));
}
template<typename T> __device__ __forceinline__ float4 load4(const T* p);
template<> __device__ __forceinline__ float4 load4<float>(const float* p) {
  return *(const float4*)p;
}
template<> __device__ __forceinline__ float4 load4<__half>(const __half* p) {
  const ushort4 u = *(const ushort4*)p;   // 8B-aligned at all call sites
  float4 r;
  r.x = h2f_bits(u.x); r.y = h2f_bits(u.y);
  r.z = h2f_bits(u.z); r.w = h2f_bits(u.w);
  return r;
}
__device__ __forceinline__ float sigmoidf(float x) {
  return 1.0f / (1.0f + expf(-x));
}
__device__ __forceinline__ float fast_tanhf(float x) {
  return 1.0f - 2.0f / (__expf(2.0f * x) + 1.0f);
}

// ---- device-scope (sc1) coherent accessors for DYNAMIC buffers ------------
__device__ __forceinline__ float loadf_dev(const float* p) {
  return __uint_as_float(__hip_atomic_load((const unsigned*)p, __ATOMIC_RELAXED,
                                           __HIP_MEMORY_SCOPE_AGENT));
}
__device__ __forceinline__ void storef_dev(float* p, float v) {
  __hip_atomic_store((unsigned*)p, __float_as_uint(v), __ATOMIC_RELAXED,
                     __HIP_MEMORY_SCOPE_AGENT);
}
__device__ __forceinline__ float4 load4_dev(const float* p) {
  const unsigned long long a = __hip_atomic_load((const unsigned long long*)p,
      __ATOMIC_RELAXED, __HIP_MEMORY_SCOPE_AGENT);
  const unsigned long long b = __hip_atomic_load((const unsigned long long*)p + 1,
      __ATOMIC_RELAXED, __HIP_MEMORY_SCOPE_AGENT);
  float4 r;
  r.x = __uint_as_float((unsigned)a);  r.y = __uint_as_float((unsigned)(a >> 32));
  r.z = __uint_as_float((unsigned)b);  r.w = __uint_as_float((unsigned)(b >> 32));
  return r;
}
__device__ __forceinline__ void store4_dev(float* p, const float4 v) {
  const unsigned long long a = (unsigned long long)__float_as_uint(v.x) |
                               ((unsigned long long)__float_as_uint(v.y) << 32);
  const unsigned long long b = (unsigned long long)__float_as_uint(v.z) |
                               ((unsigned long long)__float_as_uint(v.w) << 32);
  __hip_atomic_store((unsigned long long*)p, a, __ATOMIC_RELAXED,
                     __HIP_MEMORY_SCOPE_AGENT);
  __hip_atomic_store((unsigned long long*)p + 1, b, __ATOMIC_RELAXED,
                     __HIP_MEMORY_SCOPE_AGENT);
}
template<typename CT> __device__ __forceinline__ CT load_dev(const CT* p);
template<> __device__ __forceinline__ float load_dev<float>(const float* p) {
  return loadf_dev(p);
}
template<> __device__ __forceinline__ __half load_dev<__half>(const __half* p) {
  unsigned short u = __hip_atomic_load((const unsigned short*)p, __ATOMIC_RELAXED,
                                       __HIP_MEMORY_SCOPE_AGENT);
  __half_raw r; r.x = u; return (__half)r;
}
template<typename CT> __device__ __forceinline__ void store_dev(CT* p, CT v);
template<> __device__ __forceinline__ void store_dev<float>(float* p, float v) {
  storef_dev(p, v);
}
template<> __device__ __forceinline__ void store_dev<__half>(__half* p, __half v) {
  __half_raw r = *reinterpret_cast<__half_raw*>(&v);
  __hip_atomic_store((unsigned short*)p, r.x, __ATOMIC_RELAXED,
                     __HIP_MEMORY_SCOPE_AGENT);
}

// fp32 -> (hi bf16 truncate, lo bf16 rne of residual)
__device__ __forceinline__ void split2(float x, short& h, short& l) {
  const unsigned u  = __float_as_uint(x);
  const unsigned hu = u & 0xffff0000u;
  h = (short)(hu >> 16);
  const float r = x - __uint_as_float(hu);
  l = (short)((__float_as_uint(r) + 0x8000u) >> 16);
}
__device__ __forceinline__ void store4split(const float4 v, short* hp, short* lp) {
  short h0, h1, h2, h3, l0, l1, l2, l3;
  split2(v.x, h0, l0); split2(v.y, h1, l1);
  split2(v.z, h2, l2); split2(v.w, h3, l3);
  *(short4*)hp = make_short4(h0, h1, h2, h3);
  *(short4*)lp = make_short4(l0, l1, l2, l3);
}

// ---- distributed-arrival grid barrier (256 blocks, 1/CU) ------------------
__device__ __forceinline__ void grid_sync(unsigned* flags, unsigned* release,
                                          unsigned no) {
  __builtin_amdgcn_s_waitcnt(0);
  __syncthreads();
  if (blockIdx.x == 0) {
    const int tid = threadIdx.x;
    if (tid > 0) {
      while (__hip_atomic_load(&flags[tid * FLAG_STRIDE], __ATOMIC_RELAXED,
                               __HIP_MEMORY_SCOPE_AGENT) < no)
        __builtin_amdgcn_s_sleep(1);
    }
    __syncthreads();
    if (tid == 0)
      __hip_atomic_store(release, no, __ATOMIC_RELAXED, __HIP_MEMORY_SCOPE_AGENT);
  } else {
    if (threadIdx.x == 0) {
      __hip_atomic_store(&flags[blockIdx.x * FLAG_STRIDE], no, __ATOMIC_RELAXED,
                         __HIP_MEMORY_SCOPE_AGENT);
      while (__hip_atomic_load(release, __ATOMIC_RELAXED,
                               __HIP_MEMORY_SCOPE_AGENT) < no)
        __builtin_amdgcn_s_sleep(2);
    }
    __syncthreads();
  }
}

// ---------------------------------------------------------------------------
// Pipelined 64xN GEMM: C (+)= A[64,K]*B[N,K]^T, split-bf16 MFMA (hh,hl,lh).
// A is DYNAMIC (sc1 loads); B is static (plain cached). CSC: C via sc1.
// ---------------------------------------------------------------------------
template<typename CT, bool ACC, int NT, bool CSC>
__device__ __forceinline__ void gemm64v2(short* smem,
    const float* A, int lda, int m0,
    const float* B, int ldb, int n0, int K,
    CT* Cbase, size_t crstride, int tid) {
  constexpr int BPL  = NT * 128;             // B kgroup stride (shorts)
  constexpr int BSZ  = NT * 512;             // B plane size (shorts)
  constexpr int BUFS = 4096 + 2 * BSZ;       // shorts per LDS buffer
  const int lane = tid & 63, wave = tid >> 6, qm = lane & 15, quad = lane >> 4;
  const int ra = tid >> 3, c4 = tid & 7, j0 = (c4 & 1) * 4, gq = c4 >> 1;
  const int a0 = gq * 512 + ra * 8 + j0;
  const int a1 = gq * 512 + (ra + 32) * 8 + j0;
  const int b0 = gq * BPL + ra * 8 + j0;
  const int b1 = gq * BPL + (ra + 32) * 8 + j0;
  const int CN = K >> 5;

  floatx4 acc[NT];
#pragma unroll
  for (int nt = 0; nt < NT; ++nt) acc[nt] = (floatx4){0.f, 0.f, 0.f, 0.f};

  float4 Aa0, Aa1, Ba0, Ba1, Ab0, Ab1, Bb0, Bb1;
  auto ld = [&](int c, float4& x0, float4& x1, float4& y0, float4& y1) {
    const int k0 = c * 32 + c4 * 4;
    x0 = load4_dev(A + (size_t)(m0 + ra) * lda + k0);
    x1 = load4_dev(A + (size_t)(m0 + ra + 32) * lda + k0);
    y0 = *(const float4*)(B + (size_t)(n0 + ra) * ldb + k0);
    if (NT == 4)
      y1 = *(const float4*)(B + (size_t)(n0 + ra + 32) * ldb + k0);
  };
  auto st = [&](short* bp, const float4& x0, const float4& x1,
                const float4& y0, const float4& y1) {
    store4split(x0, bp + a0, bp + 2048 + a0);
    store4split(x1, bp + a1, bp + 2048 + a1);
    store4split(y0, bp + 4096 + b0, bp + 4096 + BSZ + b0);
    if (NT == 4) store4split(y1, bp + 4096 + b1, bp + 4096 + BSZ + b1);
  };
  auto mm = [&](const short* bp) {
    const int abase = quad * 512 + (wave * 16 + qm) * 8;
    const short8 ah = *(const short8*)&bp[abase];
    const short8 al = *(const short8*)&bp[2048 + abase];
#pragma unroll
    for (int nt = 0; nt < NT; ++nt) {
      const int bb = quad * BPL + (nt * 16 + qm) * 8;
      const short8 bh = *(const short8*)&bp[4096 + bb];
      const short8 bl = *(const short8*)&bp[4096 + BSZ + bb];
      acc[nt] = __builtin_amdgcn_mfma_f32_16x16x32_bf16(ah, bh, acc[nt], 0, 0, 0);
      acc[nt] = __builtin_amdgcn_mfma_f32_16x16x32_bf16(ah, bl, acc[nt], 0, 0, 0);
      acc[nt] = __builtin_amdgcn_mfma_f32_16x16x32_bf16(al, bh, acc[nt], 0, 0, 0);
    }
  };

  ld(0, Aa0, Aa1, Ba0, Ba1);
  if (CN > 1) ld(1, Ab0, Ab1, Bb0, Bb1);
  st(smem, Aa0, Aa1, Ba0, Ba1);
  __syncthreads();
  for (int c = 0; c < CN; c += 2) {
    if (c + 2 < CN) ld(c + 2, Aa0, Aa1, Ba0, Ba1);
    mm(smem);
    if (c + 1 < CN) st(smem + BUFS, Ab0, Ab1, Bb0, Bb1);
    __syncthreads();
    if (c + 1 < CN) {
      if (c + 3 < CN) ld(c + 3, Ab0, Ab1, Bb0, Bb1);
      mm(smem + BUFS);
      if (c + 2 < CN) st(smem, Aa0, Aa1, Ba0, Ba1);
      __syncthreads();
    }
  }

#pragma unroll
  for (int nt = 0; nt < NT; ++nt)
#pragma unroll
    for (int r2 = 0; r2 < 4; ++r2) {
      const int m = wave * 16 + quad * 4 + r2, n = nt * 16 + qm;
      CT* cp = Cbase + (size_t)m * crstride + n;
      float o = acc[nt][r2];
      if (CSC) {
        if (ACC) o += cvt_to_f<CT>(load_dev<CT>(cp));
        store_dev<CT>(cp, cvt_from_f<CT>(o));
      } else {
        if (ACC) o += cvt_to_f<CT>(*cp);
        *cp = cvt_from_f<CT>(o);
      }
    }
}

// ---------------------------------------------------------------------------
// Pipelined gate GEMM: 4 accs (i,f,g,o), out tile 64(m) x 16(h-slice)/gate.
// ---------------------------------------------------------------------------
__device__ __forceinline__ void gates_gemm_v2(floatx4 acc[4], short* smem,
    const float* A1, int lda1, const float* B1, int ldb1, int K1,
    const float* A2, int lda2, const float* B2, int ldb2, int K2,
    int m0, int hoff, int tid) {
  const int lane = tid & 63, wave = tid >> 6, qm = lane & 15, quad = lane >> 4;
  const int ra = tid >> 3, c4 = tid & 7, j0 = (c4 & 1) * 4, gq = c4 >> 1;
  const int a0 = gq * 512 + ra * 8 + j0;
  const int a1 = gq * 512 + (ra + 32) * 8 + j0;
  const int g0 = (ra >> 4) * Hn + hoff + (ra & 15);
  const int g1 = ((ra + 32) >> 4) * Hn + hoff + ((ra + 32) & 15);
  const int C1 = K1 >> 5;
  const int C2 = A2 ? (K2 >> 5) : 0;
  const int CN = C1 + C2;

  float4 Aa0, Aa1, Ba0, Ba1, Ab0, Ab1, Bb0, Bb1;
  auto ld = [&](int c, float4& x0, float4& x1, float4& y0, float4& y1) {
    const float* A; const float* B; int lda, ldb, k0;
    if (c < C1) { A = A1; B = B1; lda = lda1; ldb = ldb1; k0 = c * 32; }
    else        { A = A2; B = B2; lda = lda2; ldb = ldb2; k0 = (c - C1) * 32; }
    k0 += c4 * 4;
    x0 = load4_dev(A + (size_t)(m0 + ra) * lda + k0);
    x1 = load4_dev(A + (size_t)(m0 + ra + 32) * lda + k0);
    y0 = *(const float4*)(B + (size_t)g0 * ldb + k0);
    y1 = *(const float4*)(B + (size_t)g1 * ldb + k0);
  };
  auto st2 = [&](short* bp, const float4& x0, const float4& x1,
                 const float4& y0, const float4& y1) {
    store4split(x0, bp + a0, bp + 2048 + a0);
    store4split(x1, bp + a1, bp + 2048 + a1);
    store4split(y0, bp + 4096 + a0, bp + 6144 + a0);
    store4split(y1, bp + 4096 + a1, bp + 6144 + a1);
  };
  auto mm = [&](const short* bp) {
    const int abase = quad * 512 + (wave * 16 + qm) * 8;
    const short8 ah = *(const short8*)&bp[abase];
    const short8 al = *(const short8*)&bp[2048 + abase];
#pragma unroll
    for (int gg = 0; gg < 4; ++gg) {
      const int bb = quad * 512 + (gg * 16 + qm) * 8;
      const short8 bh = *(const short8*)&bp[4096 + bb];
      const short8 bl = *(const short8*)&bp[6144 + bb];
      acc[gg] = __builtin_amdgcn_mfma_f32_16x16x32_bf16(ah, bh, acc[gg], 0, 0, 0);
      acc[gg] = __builtin_amdgcn_mfma_f32_16x16x32_bf16(ah, bl, acc[gg], 0, 0, 0);
      acc[gg] = __builtin_amdgcn_mfma_f32_16x16x32_bf16(al, bh, acc[gg], 0, 0, 0);
    }
  };

  if (CN <= 0) return;
  ld(0, Aa0, Aa1, Ba0, Ba1);
  if (CN > 1) ld(1, Ab0, Ab1, Bb0, Bb1);
  st2(smem, Aa0, Aa1, Ba0, Ba1);
  __syncthreads();
  for (int c = 0; c < CN; c += 2) {
    if (c + 2 < CN) ld(c + 2, Aa0, Aa1, Ba0, Ba1);
    mm(smem);
    if (c + 1 < CN) st2(smem + 8192, Ab0, Ab1, Bb0, Bb1);
    __syncthreads();
    if (c + 1 < CN) {
      if (c + 3 < CN) ld(c + 3, Ab0, Ab1, Bb0, Bb1);
      mm(smem + 8192);
      if (c + 2 < CN) st2(smem, Aa0, Aa1, Ba0, Ba1);
      __syncthreads();
    }
  }
}

// ---------------------------------------------------------------------------
__global__ void weff_kernel(const float* Wih_f, const float* Wih_b,
                            const float* W_embed, float* weff_f, float* weff_b) {
  const int gidx = blockIdx.x * 256 + threadIdx.x;
  if (gidx >= G4n) return;
  float f0 = 0.f, f1 = 0.f, b0 = 0.f, b1 = 0.f;
  for (int e = 0; e < En; ++e) {
    const float w0 = W_embed[e * 2 + 0];
    const float w1 = W_embed[e * 2 + 1];
    const float wf = Wih_f[gidx * En + e];
    const float wb = Wih_b[gidx * En + e];
    f0 = fmaf(wf, w0, f0); f1 = fmaf(wf, w1, f1);
    b0 = fmaf(wb, w0, b0); b1 = fmaf(wb, w1, b1);
  }
  weff_f[gidx * 2 + 0] = f0; weff_f[gidx * 2 + 1] = f1;
  weff_b[gidx * 2 + 0] = b0; weff_b[gidx * 2 + 1] = b1;
}

// ---------------------------------------------------------------------------
// Persistent encoder: 100 steps, 1 grid-sync/step. 256 blocks.
// ---------------------------------------------------------------------------
template<typename ET, typename RT1, typename RT2>
struct EncP {
  const float* inputs;
  const float* Whh_f; const float* Whh_b;
  const float* b_f; const float* b_b;
  const float* weff_f; const float* weff_b;
  const float* W_ref; const float* W_ref2;
  float* hbuf;       // [2 parity][2 dir][512*256]  (dynamic, sc1)
  float* c_dec;      // [2 dir][512*256]            (kernel-boundary)
  float* dec_out0;   // [512*512]                   (kernel-boundary)
  ET* Enc; RT1* ref1; RT2* ref2;
  unsigned* flags; unsigned* release;
};

template<typename ET, typename RT1, typename RT2>
__global__ __launch_bounds__(256, 1) void enc_coop(EncP<ET, RT1, RT2> P) {
  __shared__ __align__(16) short smem[16384];
  const int bid = blockIdx.x, tid = threadIdx.x;
  const int dir = bid >> 7, btile = (bid >> 4) & 7, hs = bid & 15;
  const int r_ref = (bid >> 7) & 1, r_dir = (bid >> 6) & 1;
  const int r_bt = (bid >> 3) & 7, r_ns = bid & 7;
  const int lane = tid & 63, wave = tid >> 6, qm = lane & 15, quad = lane >> 4;
  const int hcol = hs * 16 + qm;
  const float* Whh  = dir ? P.Whh_b : P.Whh_f;
  const float* bias = dir ? P.b_b : P.b_f;
  const float* weff = dir ? P.weff_b : P.weff_f;
  float c_reg[4] = {0.f, 0.f, 0.f, 0.f};
  float h_reg[4] = {0.f, 0.f, 0.f, 0.f};
  unsigned sync_no = 0;

  auto ref_job = [&](const float* hpar, int pos) {
    const float* hsrc = hpar + (size_t)r_dir * (Bn * Hn);
    if (r_ref == 0)
      gemm64v2<RT1, true, 4, true>(smem, hsrc, Hn, r_bt * 64,
                             P.W_ref + r_dir * Hn, D2n, r_ns * 64, Hn,
                             P.ref1 + (size_t)(r_bt * 64) * Tn * D2n + (size_t)pos * D2n + r_ns * 64,
                             (size_t)Tn * D2n, tid);
    else
      gemm64v2<RT2, true, 4, true>(smem, hsrc, Hn, r_bt * 64,
                             P.W_ref2 + r_dir * Hn, D2n, r_ns * 64, Hn,
                             P.ref2 + (size_t)(r_bt * 64) * Tn * D2n + (size_t)pos * D2n + r_ns * 64,
                             (size_t)Tn * D2n, tid);
  };

  for (int t = 0; t < Tn; ++t) {
    const float* hprev = P.hbuf + (size_t)((t - 1) & 1) * (2 * Bn * Hn);
    if (t > 0) ref_job(hprev, r_dir ? (Tn - t) : (t - 1));
    floatx4 acc[4];
#pragma unroll
    for (int gg = 0; gg < 4; ++gg) acc[gg] = (floatx4){0.f, 0.f, 0.f, 0.f};
    if (t > 0)
      gates_gemm_v2(acc, smem, hprev + (size_t)dir * (Bn * Hn), Hn, Whh, Hn, Hn,
                    nullptr, 0, nullptr, 0, 0, btile * 64, hs * 16, tid);
    const int tcur = dir ? (Tn - 1 - t) : t;
    float xa[4], xb2[4];
#pragma unroll
    for (int r2 = 0; r2 < 4; ++r2) {
      const int m = btile * 64 + wave * 16 + quad * 4 + r2;
      xa[r2]  = P.inputs[(size_t)m * (Tn * 2) + tcur * 2 + 0];
      xb2[r2] = P.inputs[(size_t)m * (Tn * 2) + tcur * 2 + 1];
    }
    float gv[4][4];
#pragma unroll
    for (int gg = 0; gg < 4; ++gg) {
      const int grow = gg * Hn + hcol;
      const float bn = bias[grow];
      const float w20 = weff[grow * 2], w21 = weff[grow * 2 + 1];
#pragma unroll
      for (int r2 = 0; r2 < 4; ++r2) {
        float o = acc[gg][r2] + bn;
        o = fmaf(xa[r2], w20, fmaf(xb2[r2], w21, o));
        gv[gg][r2] = o;
      }
    }
    float* hdst = P.hbuf + (size_t)(t & 1) * (2 * Bn * Hn) + (size_t)dir * (Bn * Hn);
    const int tt = dir ? (Tn - 1 - t) : t;
#pragma unroll
    for (int r2 = 0; r2 < 4; ++r2) {
      const float cn = sigmoidf(gv[1][r2]) * c_reg[r2] +
                       sigmoidf(gv[0][r2]) * tanhf(gv[2][r2]);
      c_reg[r2] = cn;
      const float hn = sigmoidf(gv[3][r2]) * tanhf(cn);
      h_reg[r2] = hn;
      const int m = btile * 64 + wave * 16 + quad * 4 + r2;
      storef_dev(&hdst[(size_t)m * Hn + hcol], hn);
      store_dev<ET>(&P.Enc[(size_t)m * Tn * D2n + (size_t)tt * D2n + dir * Hn + hcol],
                    cvt_from_f<ET>(hn));
    }
    grid_sync(P.flags, P.release, ++sync_no);
  }
  ref_job(P.hbuf + (size_t)1 * (2 * Bn * Hn), r_dir ? 0 : (Tn - 1));
#pragma unroll
  for (int r2 = 0; r2 < 4; ++r2) {
    const int m = btile * 64 + wave * 16 + quad * 4 + r2;
    P.dec_out0[(size_t)m * D2n + dir * Hn + hcol] = h_reg[r2];
    P.c_dec[((size_t)dir * Bn + m) * Hn + hcol] = c_reg[r2];
  }
}

// ---------------------------------------------------------------------------
// Persistent decoder: 100 steps, 3 grid-syncs/step. 256 blocks.
// ---------------------------------------------------------------------------
template<typename ET, typename RT1, typename RT2>
struct DecP {
  const int* test_roads;
  const float* Wih_f; const float* Whh_f; const float* b_f;
  const float* Wih_b; const float* Whh_b; const float* b_b;
  const float* W_q; const float* W_q2; const float* v; const float* v2;
  const ET* Enc; const RT1* ref1; const RT2* ref2;
  float* dec_out;    // [2][512*512] (dynamic, sc1)
  float* xb;         // [2][512*512] (dynamic, sc1)
  float* qb; float* q2b;            // (dynamic, sc1)
  const float* c_init;  // [2][512*256] (kernel-boundary)
  float* loss;       // d_out [512]
  unsigned* flags; unsigned* release;
};

template<typename ET, typename RT1, typename RT2>
__global__ __launch_bounds__(256, 1) void dec_coop(DecP<ET, RT1, RT2> P) {
  __shared__ __align__(16) short smem[16384];
  __shared__ float s1l[2][104], s2l[2][104];
  __shared__ float awl[2][104];
  __shared__ float redf[2][128];
  __shared__ int   redi[2][128];
  __shared__ float playedl[2][104];
  __shared__ float lossl[2];
  const int bid = blockIdx.x, tid = threadIdx.x;
  const int dir = bid >> 7, btile = (bid >> 4) & 7, hs = bid & 15;
  const int lane = tid & 63, wave = tid >> 6, qm = lane & 15, quad = lane >> 4;
  const int hcol = hs * 16 + qm;
  const float* Wih  = dir ? P.Wih_b : P.Wih_f;
  const float* Whh  = dir ? P.Whh_b : P.Whh_f;
  const float* bias = dir ? P.b_b : P.b_f;
  float c_reg[4];
#pragma unroll
  for (int r2 = 0; r2 < 4; ++r2) {
    const int m = btile * 64 + wave * 16 + quad * 4 + r2;
    c_reg[r2] = P.c_init[((size_t)dir * Bn + m) * Hn + hcol];
  }
  if (tid < Tn) { playedl[0][tid] = 0.f; playedl[1][tid] = 0.f; }
  if (tid < 2) lossl[tid] = 0.f;
  // P2: 256 jobs of 64x32
  const int proj = bid >> 7, pbt = (bid >> 4) & 7, pn = bid & 15;
  // P3 mapping: wave -> (local b, attn)
  const int ab = wave >> 1, attn = wave & 1;
  const int gb = bid * 2 + ab;
  const int half = tid >> 7, htid = tid & 127;
  unsigned sync_no = 0;
  __syncthreads();

  for (int t = 0; t < Tn; ++t) {
    const float* xc  = P.xb + (size_t)(t & 1) * (Bn * D2n);
    const float* dcur = P.dec_out + (size_t)(t & 1) * (Bn * D2n);
    float* dnext = P.dec_out + (size_t)((t + 1) & 1) * (Bn * D2n);
    // ---- P1: cell gates + LSTM ----
    floatx4 acc[4];
#pragma unroll
    for (int gg = 0; gg < 4; ++gg) acc[gg] = (floatx4){0.f, 0.f, 0.f, 0.f};
    gates_gemm_v2(acc, smem, xc, D2n, Wih, D2n, D2n,
                  dcur + dir * Hn, D2n, Whh, Hn, Hn, btile * 64, hs * 16, tid);
#pragma unroll
    for (int gg = 0; gg < 4; ++gg) {
      const float bn = bias[gg * Hn + hcol];
#pragma unroll
      for (int r2 = 0; r2 < 4; ++r2) acc[gg][r2] += bn;
    }
#pragma unroll
    for (int r2 = 0; r2 < 4; ++r2) {
      const float cn = sigmoidf(acc[1][r2]) * c_reg[r2] +
                       sigmoidf(acc[0][r2]) * tanhf(acc[2][r2]);
      c_reg[r2] = cn;
      const float hn = sigmoidf(acc[3][r2]) * tanhf(cn);
      const int m = btile * 64 + wave * 16 + quad * 4 + r2;
      storef_dev(&dnext[(size_t)m * D2n + dir * Hn + hcol], hn);
    }
    grid_sync(P.flags, P.release, ++sync_no);
    // ---- P2: q projections (256 jobs, 64x32 tiles) ----
    {
      const float* A = proj ? xc : dnext;
      const float* B = proj ? P.W_q2 : P.W_q;
      float* C = (proj ? P.q2b : P.qb) + (size_t)(pbt * 64) * D2n + pn * 32;
      gemm64v2<float, false, 2, true>(smem, A, D2n, pbt * 64, B, D2n, pn * 32, D2n,
                                      C, D2n, tid);
    }
    grid_sync(P.flags, P.release, ++sync_no);
    // ---- P3: attention, 10-row groups, static ping-pong prefetch ----
    {
      const float* qrow = (attn ? P.q2b : P.qb) + (size_t)gb * D2n;
      const float* vp = attn ? P.v2 : P.v;
      const int e0 = lane * 4, e1 = (64 + lane) * 4;
      const float4 q0 = load4_dev(qrow + e0);
      const float4 q1 = load4_dev(qrow + e1);
      const float4 v0 = *(const float4*)&vp[e0];
      const float4 v1 = *(const float4*)&vp[e1];
      float* sdst = attn ? &s2l[ab][0] : &s1l[ab][0];
      float4 Ra0[10], Ra1[10], Rb0[10], Rb1[10];
      auto ldg = [&](int jb, float4 (&R0)[10], float4 (&R1)[10]) {
#pragma unroll
        for (int jj = 0; jj < 10; ++jj) {
          if (attn == 0) {
            const RT1* row = P.ref1 + ((size_t)gb * Tn + jb + jj) * D2n;
            R0[jj] = load4<RT1>(row + e0); R1[jj] = load4<RT1>(row + e1);
          } else {
            const RT2* row = P.ref2 + ((size_t)gb * Tn + jb + jj) * D2n;
            R0[jj] = load4<RT2>(row + e0); R1[jj] = load4<RT2>(row + e1);
          }
        }
      };
      auto cmp = [&](int jb, const float4 (&R0)[10], const float4 (&R1)[10]) {
#pragma unroll
        for (int jj = 0; jj < 10; ++jj) {
          const float4 r0 = R0[jj], r1 = R1[jj];
          float a = 0.f;
          a = fmaf(fast_tanhf(r0.x + q0.x), v0.x, a);
          a = fmaf(fast_tanhf(r0.y + q0.y), v0.y, a);
          a = fmaf(fast_tanhf(r0.z + q0.z), v0.z, a);
          a = fmaf(fast_tanhf(r0.w + q0.w), v0.w, a);
          a = fmaf(fast_tanhf(r1.x + q1.x), v1.x, a);
          a = fmaf(fast_tanhf(r1.y + q1.y), v1.y, a);
          a = fmaf(fast_tanhf(r1.z + q1.z), v1.z, a);
          a = fmaf(fast_tanhf(r1.w + q1.w), v1.w, a);
#pragma unroll
          for (int off = 32; off > 0; off >>= 1) a += __shfl_xor(a, off, 64);
          if (lane == 0) sdst[jb + jj] = a;
        }
      };
      ldg(0, Ra0, Ra1);
      for (int g = 0; g < 10; g += 2) {
        if (g + 1 < 10) ldg((g + 1) * 10, Rb0, Rb1);
        cmp(g * 10, Ra0, Ra1);
        if (g + 2 < 10) ldg((g + 2) * 10, Ra0, Ra1);
        if (g + 1 < 10) cmp((g + 1) * 10, Rb0, Rb1);
      }
    }
    __syncthreads();
    // ---- P4: both owned b's in parallel on half-blocks ----
    {
      float* xnextbuf = P.xb + (size_t)((t + 1) & 1) * (Bn * D2n);
      const int b = bid * 2 + half;
      float* rf = &redf[half][0];
      int*   ri = &redi[half][0];
      const float uval = (htid < Tn) ? s2l[half][htid] : -INFINITY;
      const float owval = (htid < Tn) ? (s1l[half][htid] - PENf * playedl[half][htid])
                                      : -INFINITY;
      rf[htid] = uval; __syncthreads();
      for (int s = 64; s > 0; s >>= 1) {
        if (htid < s) rf[htid] = fmaxf(rf[htid], rf[htid + s]);
        __syncthreads();
      }
      const float umax = rf[0]; __syncthreads();
      const float e = (htid < Tn) ? __expf(uval - umax) : 0.f;
      rf[htid] = e; __syncthreads();
      for (int s = 64; s > 0; s >>= 1) {
        if (htid < s) rf[htid] += rf[htid + s];
        __syncthreads();
      }
      const float usum = rf[0]; __syncthreads();
      if (htid < Tn) awl[half][htid] = e / usum;
      rf[htid] = owval; ri[htid] = (htid < Tn) ? htid : 0x7fffffff; __syncthreads();
      for (int s = 64; s > 0; s >>= 1) {
        if (htid < s) {
          const float ov = rf[htid + s]; const int oi = ri[htid + s];
          if (ov > rf[htid] || (ov == rf[htid] && oi < ri[htid])) {
            rf[htid] = ov; ri[htid] = oi;
          }
        }
        __syncthreads();
      }
      const float omax = rf[0]; const int sel = ri[0]; __syncthreads();
      const float eo = (htid < Tn) ? __expf(owval - omax) : 0.f;
      rf[htid] = eo; __syncthreads();
      for (int s = 64; s > 0; s >>= 1) {
        if (htid < s) rf[htid] += rf[htid + s];
        __syncthreads();
      }
      if (htid == 0) {
        const float lse = omax + __logf(rf[0]);
        const int tgt = P.test_roads[b * Tn + t];
        const float owt = s1l[half][tgt] - PENf * playedl[half][tgt];
        lossl[half] += lse - owt;
        playedl[half][sel] += 1.f;
      }
      __syncthreads();
      // x_new: per-thread float4 over 4 cols, 10-row groups, static ping-pong
      const ET* Eb = P.Enc + (size_t)b * Tn * D2n;
      float* xn = xnextbuf + (size_t)b * D2n;
      const int k4 = htid * 4;            // 128 threads * 4 = 512 cols
      float4 Ea[10], Eb2[10];
      auto lde = [&](int jb, float4 (&E)[10]) {
#pragma unroll
        for (int jj = 0; jj < 10; ++jj)
          E[jj] = load4<ET>(Eb + (size_t)(jb + jj) * D2n + k4);
      };
      float4 a4 = {0.f, 0.f, 0.f, 0.f};
      auto ac4 = [&](int jb, const float4 (&E)[10]) {
#pragma unroll
        for (int jj = 0; jj < 10; ++jj) {
          const float w = awl[half][jb + jj];
          a4.x = fmaf(w, E[jj].x, a4.x);
          a4.y = fmaf(w, E[jj].y, a4.y);
          a4.z = fmaf(w, E[jj].z, a4.z);
          a4.w = fmaf(w, E[jj].w, a4.w);
        }
      };
      lde(0, Ea);
      for (int g = 0; g < 10; g += 2) {
        if (g + 1 < 10) lde((g + 1) * 10, Eb2);
        ac4(g * 10, Ea);
        if (g + 2 < 10) lde((g + 2) * 10, Ea);
        if (g + 1 < 10) ac4((g + 1) * 10, Eb2);
      }
      store4_dev(&xn[k4], a4);
    }
    grid_sync(P.flags, P.release, ++sync_no);
  }
  if (tid == 0) {
    P.loss[bid * 2]     = lossl[0];
    P.loss[bid * 2 + 1] = lossl[1];
  }
}

// ---------------------------------------------------------------------------
// Refs + Enc stored as fp16 UNCONDITIONALLY: per-step read working set drops
// 315 MB (f32) -> 157 MB < 256 MB LLC, so the decoder's ref/Enc stream stays
// LLC-resident instead of thrashing to HBM (r12 counters: 122 MB/step HBM
// fetch at 834 GB/s = 146 us = the whole step time). Gates/q/x/ow stay fp32.
// ---------------------------------------------------------------------------
static void run_all(void* const* d_in, void* d_out, char* ws, hipStream_t stream) {
  using ET = __half; using RT1 = __half; using RT2 = __half;
  const float* inputs     = (const float*)d_in[0];
  const int*   test_roads = (const int*)d_in[1];
  const float* W_embed    = (const float*)d_in[2];
  const float* enc_Wih_f  = (const float*)d_in[3];
  const float* enc_Whh_f  = (const float*)d_in[4];
  const float* enc_b_f    = (const float*)d_in[5];
  const float* enc_Wih_b  = (const float*)d_in[6];
  const float* enc_Whh_b  = (const float*)d_in[7];
  const float* enc_b_b    = (const float*)d_in[8];
  const float* dec_Wih_f  = (const float*)d_in[9];
  const float* dec_Whh_f  = (const float*)d_in[10];
  const float* dec_b_f    = (const float*)d_in[11];
  const float* dec_Wih_b  = (const float*)d_in[12];
  const float* dec_Whh_b  = (const float*)d_in[13];
  const float* dec_b_b    = (const float*)d_in[14];
  const float* W_ref      = (const float*)d_in[15];
  const float* W_q        = (const float*)d_in[16];
  const float* v          = (const float*)d_in[17];
  const float* W_ref2     = (const float*)d_in[18];
  const float* W_q2       = (const float*)d_in[19];
  const float* v2         = (const float*)d_in[20];

  char* p0 = ws;
  ET*  Enc  = (ET*)p0;  p0 += BIGN * sizeof(ET);
  RT1* ref1 = (RT1*)p0; p0 += BIGN * sizeof(RT1);
  RT2* ref2 = (RT2*)p0; p0 += BIGN * sizeof(RT2);
  unsigned* flagsE = (unsigned*)p0;                 // 256 padded lines
  unsigned* relE   = flagsE + 256 * FLAG_STRIDE;
  unsigned* flagsD = relE + 32;
  unsigned* relD   = flagsD + 256 * FLAG_STRIDE;
  float* xb      = (float*)(p0 + BAR_UINTS * 4);
  float* dec_out = xb + 2 * Bn * D2n;               // 2 * 512*512
  float* hbuf    = dec_out + 2 * Bn * D2n;          // 2 * 2 * 512*256
  float* c_dec   = hbuf + 4 * Bn * Hn;              // 2 * 512*256
  float* qb      = c_dec + 2 * Bn * Hn;
  float* q2b     = qb + Bn * D2n;
  float* weff_f  = q2b + Bn * D2n;
  float* weff_b  = weff_f + G4n * 2;

  hipMemsetAsync(ref1, 0, BIGN * (sizeof(RT1) + sizeof(RT2)), stream);
  hipMemsetAsync(flagsE, 0, BAR_UINTS * 4 + (size_t)Bn * D2n * 4, stream);

  weff_kernel<<<G4n / 256, 256, 0, stream>>>(enc_Wih_f, enc_Wih_b, W_embed,
                                             weff_f, weff_b);

  EncP<ET, RT1, RT2> ep = { inputs, enc_Whh_f, enc_Whh_b, enc_b_f, enc_b_b,
                            weff_f, weff_b, W_ref, W_ref2,
                            hbuf, c_dec, dec_out, Enc, ref1, ref2,
                            flagsE, relE };
  enc_coop<ET, RT1, RT2><<<256, 256, 0, stream>>>(ep);

  DecP<ET, RT1, RT2> dp = { test_roads,
                            dec_Wih_f, dec_Whh_f, dec_b_f,
                            dec_Wih_b, dec_Whh_b, dec_b_b,
                            W_q, W_q2, v, v2,
                            Enc, ref1, ref2,
                            dec_out, xb, qb, q2b, c_dec,
                            (float*)d_out, flagsD, relD };
  dec_coop<ET, RT1, RT2><<<256, 256, 0, stream>>>(dp);
}

// ---------------------------------------------------------------------------
extern "C" void kernel_launch(void* const* d_in, const int* in_sizes, int n_in,
                              void* d_out, int out_size, void* d_ws, size_t ws_size,
                              hipStream_t stream) {
  (void)in_sizes; (void)n_in; (void)out_size; (void)ws_size;
  run_all(d_in, d_out, (char*)d_ws, stream);
}

// Round 14
// 13127.486 us; speedup vs baseline: 1.6139x; 1.0644x over previous
//
#include <hip/hip_runtime.h>
#include <hip/hip_fp16.h>
#include <math.h>

namespace {
constexpr int Bn  = 512;
constexpr int Tn  = 100;
constexpr int Hn  = 256;
constexpr int En  = 256;
constexpr int D2n = 512;
constexpr int G4n = 1024;
constexpr float PENf = 1e6f;
constexpr size_t BIGN = (size_t)Bn * Tn * D2n;   // 26,214,400 elements
constexpr int FLAG_STRIDE = 32;                  // 128 B per flag line
constexpr size_t BAR_UINTS = (256 + 512) * FLAG_STRIDE + 64;
}

using short8  = __attribute__((ext_vector_type(8))) short;
using floatx4 = __attribute__((ext_vector_type(4))) float;

// ---- type conversion helpers ----------------------------------------------
template<typename T> __device__ __forceinline__ float cvt_to_f(T x);
template<> __device__ __forceinline__ float cvt_to_f<float>(float x) { return x; }
template<> __device__ __forceinline__ float cvt_to_f<__half>(__half x) {
  return __half2float(x);
}
template<typename T> __device__ __forceinline__ T cvt_from_f(float x);
template<> __device__ __forceinline__ float cvt_from_f<float>(float x) { return x; }
template<> __device__ __forceinline__ __half cvt_from_f<__half>(float x) {
  return __float2half(x);
}
__device__ __forceinline__ float h2f_bits(unsigned short b) {
  __half_raw r; r.x = b; return __half2float(__half(r));
}
template<typename T> __device__ __forceinline__ float4 load4(const T* p);
template<> __device__ __forceinline__ float4 load4<float>(const float* p) {
  return *(const float4*)p;
}
template<> __device__ __forceinline__ float4 load4<__half>(const __half* p) {
  const ushort4 u = *(const ushort4*)p;   // 8B-aligned at all call sites
  float4 r;
  r.x = h2f_bits(u.x); r.y = h2f_bits(u.y);
  r.z = h2f_bits(u.z); r.w = h2f_bits(u.w);
  return r;
}
__device__ __forceinline__ float2 load2h(const __half* p) {
  const ushort2 u = *(const ushort2*)p;   // 4B-aligned
  float2 r; r.x = h2f_bits(u.x); r.y = h2f_bits(u.y); return r;
}
__device__ __forceinline__ float sigmoidf(float x) {
  return 1.0f / (1.0f + expf(-x));
}
__device__ __forceinline__ float fast_tanhf(float x) {
  return 1.0f - 2.0f / (__expf(2.0f * x) + 1.0f);
}

// ---- device-scope (sc1) coherent accessors for DYNAMIC buffers ------------
__device__ __forceinline__ float loadf_dev(const float* p) {
  return __uint_as_float(__hip_atomic_load((const unsigned*)p, __ATOMIC_RELAXED,
                                           __HIP_MEMORY_SCOPE_AGENT));
}
__device__ __forceinline__ void storef_dev(float* p, float v) {
  __hip_atomic_store((unsigned*)p, __float_as_uint(v), __ATOMIC_RELAXED,
                     __HIP_MEMORY_SCOPE_AGENT);
}
__device__ __forceinline__ float4 load4_dev(const float* p) {
  const unsigned long long a = __hip_atomic_load((const unsigned long long*)p,
      __ATOMIC_RELAXED, __HIP_MEMORY_SCOPE_AGENT);
  const unsigned long long b = __hip_atomic_load((const unsigned long long*)p + 1,
      __ATOMIC_RELAXED, __HIP_MEMORY_SCOPE_AGENT);
  float4 r;
  r.x = __uint_as_float((unsigned)a);  r.y = __uint_as_float((unsigned)(a >> 32));
  r.z = __uint_as_float((unsigned)b);  r.w = __uint_as_float((unsigned)(b >> 32));
  return r;
}
__device__ __forceinline__ void store2_dev(float* p, const float2 v) {
  const unsigned long long a = (unsigned long long)__float_as_uint(v.x) |
                               ((unsigned long long)__float_as_uint(v.y) << 32);
  __hip_atomic_store((unsigned long long*)p, a, __ATOMIC_RELAXED,
                     __HIP_MEMORY_SCOPE_AGENT);
}
template<typename CT> __device__ __forceinline__ CT load_dev(const CT* p);
template<> __device__ __forceinline__ float load_dev<float>(const float* p) {
  return loadf_dev(p);
}
template<> __device__ __forceinline__ __half load_dev<__half>(const __half* p) {
  unsigned short u = __hip_atomic_load((const unsigned short*)p, __ATOMIC_RELAXED,
                                       __HIP_MEMORY_SCOPE_AGENT);
  __half_raw r; r.x = u; return (__half)r;
}
template<typename CT> __device__ __forceinline__ void store_dev(CT* p, CT v);
template<> __device__ __forceinline__ void store_dev<float>(float* p, float v) {
  storef_dev(p, v);
}
template<> __device__ __forceinline__ void store_dev<__half>(__half* p, __half v) {
  __half_raw r = *reinterpret_cast<__half_raw*>(&v);
  __hip_atomic_store((unsigned short*)p, r.x, __ATOMIC_RELAXED,
                     __HIP_MEMORY_SCOPE_AGENT);
}

// fp32 -> (hi bf16 truncate, lo bf16 rne of residual)
__device__ __forceinline__ void split2(float x, short& h, short& l) {
  const unsigned u  = __float_as_uint(x);
  const unsigned hu = u & 0xffff0000u;
  h = (short)(hu >> 16);
  const float r = x - __uint_as_float(hu);
  l = (short)((__float_as_uint(r) + 0x8000u) >> 16);
}
__device__ __forceinline__ void store4split(const float4 v, short* hp, short* lp) {
  short h0, h1, h2, h3, l0, l1, l2, l3;
  split2(v.x, h0, l0); split2(v.y, h1, l1);
  split2(v.z, h2, l2); split2(v.w, h3, l3);
  *(short4*)hp = make_short4(h0, h1, h2, h3);
  *(short4*)lp = make_short4(l0, l1, l2, l3);
}

// ---- distributed-arrival grid barriers ------------------------------------
__device__ __forceinline__ void grid_sync256(unsigned* flags, unsigned* release,
                                             unsigned no) {
  __builtin_amdgcn_s_waitcnt(0);
  __syncthreads();
  if (blockIdx.x == 0) {
    const int tid = threadIdx.x;
    if (tid > 0) {
      while (__hip_atomic_load(&flags[tid * FLAG_STRIDE], __ATOMIC_RELAXED,
                               __HIP_MEMORY_SCOPE_AGENT) < no)
        __builtin_amdgcn_s_sleep(1);
    }
    __syncthreads();
    if (tid == 0)
      __hip_atomic_store(release, no, __ATOMIC_RELAXED, __HIP_MEMORY_SCOPE_AGENT);
  } else {
    if (threadIdx.x == 0) {
      __hip_atomic_store(&flags[blockIdx.x * FLAG_STRIDE], no, __ATOMIC_RELAXED,
                         __HIP_MEMORY_SCOPE_AGENT);
      while (__hip_atomic_load(release, __ATOMIC_RELAXED,
                               __HIP_MEMORY_SCOPE_AGENT) < no)
        __builtin_amdgcn_s_sleep(2);
    }
    __syncthreads();
  }
}

__device__ __forceinline__ void grid_sync512(unsigned* flags, unsigned* release,
                                             unsigned no) {
  __builtin_amdgcn_s_waitcnt(0);
  __syncthreads();
  if (blockIdx.x == 0) {
    const int tid = threadIdx.x;
    if (tid > 0) {
      while (__hip_atomic_load(&flags[tid * FLAG_STRIDE], __ATOMIC_RELAXED,
                               __HIP_MEMORY_SCOPE_AGENT) < no)
        __builtin_amdgcn_s_sleep(1);
    }
    while (__hip_atomic_load(&flags[(256 + tid) * FLAG_STRIDE], __ATOMIC_RELAXED,
                             __HIP_MEMORY_SCOPE_AGENT) < no)
      __builtin_amdgcn_s_sleep(1);
    __syncthreads();
    if (tid == 0)
      __hip_atomic_store(release, no, __ATOMIC_RELAXED, __HIP_MEMORY_SCOPE_AGENT);
  } else {
    if (threadIdx.x == 0) {
      __hip_atomic_store(&flags[blockIdx.x * FLAG_STRIDE], no, __ATOMIC_RELAXED,
                         __HIP_MEMORY_SCOPE_AGENT);
      while (__hip_atomic_load(release, __ATOMIC_RELAXED,
                               __HIP_MEMORY_SCOPE_AGENT) < no)
        __builtin_amdgcn_s_sleep(2);
    }
    __syncthreads();
  }
}

// ---------------------------------------------------------------------------
// Pipelined 64xN GEMM: C (+)= A[64,K]*B[N,K]^T, split-bf16 MFMA (hh,hl,lh).
// ---------------------------------------------------------------------------
template<typename CT, bool ACC, int NT, bool CSC>
__device__ __forceinline__ void gemm64v2(short* smem,
    const float* A, int lda, int m0,
    const float* B, int ldb, int n0, int K,
    CT* Cbase, size_t crstride, int tid) {
  constexpr int BPL  = NT * 128;
  constexpr int BSZ  = NT * 512;
  constexpr int BUFS = 4096 + 2 * BSZ;
  const int lane = tid & 63, wave = tid >> 6, qm = lane & 15, quad = lane >> 4;
  const int ra = tid >> 3, c4 = tid & 7, j0 = (c4 & 1) * 4, gq = c4 >> 1;
  const int a0 = gq * 512 + ra * 8 + j0;
  const int a1 = gq * 512 + (ra + 32) * 8 + j0;
  const int b0 = gq * BPL + ra * 8 + j0;
  const int b1 = gq * BPL + (ra + 32) * 8 + j0;
  const int CN = K >> 5;

  floatx4 acc[NT];
#pragma unroll
  for (int nt = 0; nt < NT; ++nt) acc[nt] = (floatx4){0.f, 0.f, 0.f, 0.f};

  float4 Aa0, Aa1, Ba0, Ba1, Ab0, Ab1, Bb0, Bb1;
  auto ld = [&](int c, float4& x0, float4& x1, float4& y0, float4& y1) {
    const int k0 = c * 32 + c4 * 4;
    x0 = load4_dev(A + (size_t)(m0 + ra) * lda + k0);
    x1 = load4_dev(A + (size_t)(m0 + ra + 32) * lda + k0);
    y0 = *(const float4*)(B + (size_t)(n0 + ra) * ldb + k0);
    if (NT == 4)
      y1 = *(const float4*)(B + (size_t)(n0 + ra + 32) * ldb + k0);
  };
  auto st = [&](short* bp, const float4& x0, const float4& x1,
                const float4& y0, const float4& y1) {
    store4split(x0, bp + a0, bp + 2048 + a0);
    store4split(x1, bp + a1, bp + 2048 + a1);
    store4split(y0, bp + 4096 + b0, bp + 4096 + BSZ + b0);
    if (NT == 4) store4split(y1, bp + 4096 + b1, bp + 4096 + BSZ + b1);
  };
  auto mm = [&](const short* bp) {
    const int abase = quad * 512 + (wave * 16 + qm) * 8;
    const short8 ah = *(const short8*)&bp[abase];
    const short8 al = *(const short8*)&bp[2048 + abase];
#pragma unroll
    for (int nt = 0; nt < NT; ++nt) {
      const int bb = quad * BPL + (nt * 16 + qm) * 8;
      const short8 bh = *(const short8*)&bp[4096 + bb];
      const short8 bl = *(const short8*)&bp[4096 + BSZ + bb];
      acc[nt] = __builtin_amdgcn_mfma_f32_16x16x32_bf16(ah, bh, acc[nt], 0, 0, 0);
      acc[nt] = __builtin_amdgcn_mfma_f32_16x16x32_bf16(ah, bl, acc[nt], 0, 0, 0);
      acc[nt] = __builtin_amdgcn_mfma_f32_16x16x32_bf16(al, bh, acc[nt], 0, 0, 0);
    }
  };

  ld(0, Aa0, Aa1, Ba0, Ba1);
  if (CN > 1) ld(1, Ab0, Ab1, Bb0, Bb1);
  st(smem, Aa0, Aa1, Ba0, Ba1);
  __syncthreads();
  for (int c = 0; c < CN; c += 2) {
    if (c + 2 < CN) ld(c + 2, Aa0, Aa1, Ba0, Ba1);
    mm(smem);
    if (c + 1 < CN) st(smem + BUFS, Ab0, Ab1, Bb0, Bb1);
    __syncthreads();
    if (c + 1 < CN) {
      if (c + 3 < CN) ld(c + 3, Ab0, Ab1, Bb0, Bb1);
      mm(smem + BUFS);
      if (c + 2 < CN) st(smem, Aa0, Aa1, Ba0, Ba1);
      __syncthreads();
    }
  }

#pragma unroll
  for (int nt = 0; nt < NT; ++nt)
#pragma unroll
    for (int r2 = 0; r2 < 4; ++r2) {
      const int m = wave * 16 + quad * 4 + r2, n = nt * 16 + qm;
      CT* cp = Cbase + (size_t)m * crstride + n;
      float o = acc[nt][r2];
      if (CSC) {
        if (ACC) o += cvt_to_f<CT>(load_dev<CT>(cp));
        store_dev<CT>(cp, cvt_from_f<CT>(o));
      } else {
        if (ACC) o += cvt_to_f<CT>(*cp);
        *cp = cvt_from_f<CT>(o);
      }
    }
}

// ---------------------------------------------------------------------------
// Pipelined gate GEMM: 4 accs (i,f,g,o), out tile 64(m) x 16(h-slice)/gate.
// ---------------------------------------------------------------------------
__device__ __forceinline__ void gates_gemm_v2(floatx4 acc[4], short* smem,
    const float* A1, int lda1, const float* B1, int ldb1, int K1,
    const float* A2, int lda2, const float* B2, int ldb2, int K2,
    int m0, int hoff, int tid) {
  const int lane = tid & 63, wave = tid >> 6, qm = lane & 15, quad = lane >> 4;
  const int ra = tid >> 3, c4 = tid & 7, j0 = (c4 & 1) * 4, gq = c4 >> 1;
  const int a0 = gq * 512 + ra * 8 + j0;
  const int a1 = gq * 512 + (ra + 32) * 8 + j0;
  const int g0 = (ra >> 4) * Hn + hoff + (ra & 15);
  const int g1 = ((ra + 32) >> 4) * Hn + hoff + ((ra + 32) & 15);
  const int C1 = K1 >> 5;
  const int C2 = A2 ? (K2 >> 5) : 0;
  const int CN = C1 + C2;

  float4 Aa0, Aa1, Ba0, Ba1, Ab0, Ab1, Bb0, Bb1;
  auto ld = [&](int c, float4& x0, float4& x1, float4& y0, float4& y1) {
    const float* A; const float* B; int lda, ldb, k0;
    if (c < C1) { A = A1; B = B1; lda = lda1; ldb = ldb1; k0 = c * 32; }
    else        { A = A2; B = B2; lda = lda2; ldb = ldb2; k0 = (c - C1) * 32; }
    k0 += c4 * 4;
    x0 = load4_dev(A + (size_t)(m0 + ra) * lda + k0);
    x1 = load4_dev(A + (size_t)(m0 + ra + 32) * lda + k0);
    y0 = *(const float4*)(B + (size_t)g0 * ldb + k0);
    y1 = *(const float4*)(B + (size_t)g1 * ldb + k0);
  };
  auto st2 = [&](short* bp, const float4& x0, const float4& x1,
                 const float4& y0, const float4& y1) {
    store4split(x0, bp + a0, bp + 2048 + a0);
    store4split(x1, bp + a1, bp + 2048 + a1);
    store4split(y0, bp + 4096 + a0, bp + 6144 + a0);
    store4split(y1, bp + 4096 + a1, bp + 6144 + a1);
  };
  auto mm = [&](const short* bp) {
    const int abase = quad * 512 + (wave * 16 + qm) * 8;
    const short8 ah = *(const short8*)&bp[abase];
    const short8 al = *(const short8*)&bp[2048 + abase];
#pragma unroll
    for (int gg = 0; gg < 4; ++gg) {
      const int bb = quad * 512 + (gg * 16 + qm) * 8;
      const short8 bh = *(const short8*)&bp[4096 + bb];
      const short8 bl = *(const short8*)&bp[6144 + bb];
      acc[gg] = __builtin_amdgcn_mfma_f32_16x16x32_bf16(ah, bh, acc[gg], 0, 0, 0);
      acc[gg] = __builtin_amdgcn_mfma_f32_16x16x32_bf16(ah, bl, acc[gg], 0, 0, 0);
      acc[gg] = __builtin_amdgcn_mfma_f32_16x16x32_bf16(al, bh, acc[gg], 0, 0, 0);
    }
  };

  if (CN <= 0) return;
  ld(0, Aa0, Aa1, Ba0, Ba1);
  if (CN > 1) ld(1, Ab0, Ab1, Bb0, Bb1);
  st2(smem, Aa0, Aa1, Ba0, Ba1);
  __syncthreads();
  for (int c = 0; c < CN; c += 2) {
    if (c + 2 < CN) ld(c + 2, Aa0, Aa1, Ba0, Ba1);
    mm(smem);
    if (c + 1 < CN) st2(smem + 8192, Ab0, Ab1, Bb0, Bb1);
    __syncthreads();
    if (c + 1 < CN) {
      if (c + 3 < CN) ld(c + 3, Ab0, Ab1, Bb0, Bb1);
      mm(smem + 8192);
      if (c + 2 < CN) st2(smem, Aa0, Aa1, Ba0, Ba1);
      __syncthreads();
    }
  }
}

// ---------------------------------------------------------------------------
__global__ void weff_kernel(const float* Wih_f, const float* Wih_b,
                            const float* W_embed, float* weff_f, float* weff_b) {
  const int gidx = blockIdx.x * 256 + threadIdx.x;
  if (gidx >= G4n) return;
  float f0 = 0.f, f1 = 0.f, b0 = 0.f, b1 = 0.f;
  for (int e = 0; e < En; ++e) {
    const float w0 = W_embed[e * 2 + 0];
    const float w1 = W_embed[e * 2 + 1];
    const float wf = Wih_f[gidx * En + e];
    const float wb = Wih_b[gidx * En + e];
    f0 = fmaf(wf, w0, f0); f1 = fmaf(wf, w1, f1);
    b0 = fmaf(wb, w0, b0); b1 = fmaf(wb, w1, b1);
  }
  weff_f[gidx * 2 + 0] = f0; weff_f[gidx * 2 + 1] = f1;
  weff_b[gidx * 2 + 0] = b0; weff_b[gidx * 2 + 1] = b1;
}

// ---------------------------------------------------------------------------
// Persistent encoder: 100 steps, 1 grid-sync/step. 256 blocks (unchanged).
// ---------------------------------------------------------------------------
template<typename ET, typename RT1, typename RT2>
struct EncP {
  const float* inputs;
  const float* Whh_f; const float* Whh_b;
  const float* b_f; const float* b_b;
  const float* weff_f; const float* weff_b;
  const float* W_ref; const float* W_ref2;
  float* hbuf;
  float* c_dec;
  float* dec_out0;
  ET* Enc; RT1* ref1; RT2* ref2;
  unsigned* flags; unsigned* release;
};

template<typename ET, typename RT1, typename RT2>
__global__ __launch_bounds__(256, 1) void enc_coop(EncP<ET, RT1, RT2> P) {
  __shared__ __align__(16) short smem[16384];
  const int bid = blockIdx.x, tid = threadIdx.x;
  const int dir = bid >> 7, btile = (bid >> 4) & 7, hs = bid & 15;
  const int r_ref = (bid >> 7) & 1, r_dir = (bid >> 6) & 1;
  const int r_bt = (bid >> 3) & 7, r_ns = bid & 7;
  const int lane = tid & 63, wave = tid >> 6, qm = lane & 15, quad = lane >> 4;
  const int hcol = hs * 16 + qm;
  const float* Whh  = dir ? P.Whh_b : P.Whh_f;
  const float* bias = dir ? P.b_b : P.b_f;
  const float* weff = dir ? P.weff_b : P.weff_f;
  float c_reg[4] = {0.f, 0.f, 0.f, 0.f};
  float h_reg[4] = {0.f, 0.f, 0.f, 0.f};
  unsigned sync_no = 0;

  auto ref_job = [&](const float* hpar, int pos) {
    const float* hsrc = hpar + (size_t)r_dir * (Bn * Hn);
    if (r_ref == 0)
      gemm64v2<RT1, true, 4, true>(smem, hsrc, Hn, r_bt * 64,
                             P.W_ref + r_dir * Hn, D2n, r_ns * 64, Hn,
                             P.ref1 + (size_t)(r_bt * 64) * Tn * D2n + (size_t)pos * D2n + r_ns * 64,
                             (size_t)Tn * D2n, tid);
    else
      gemm64v2<RT2, true, 4, true>(smem, hsrc, Hn, r_bt * 64,
                             P.W_ref2 + r_dir * Hn, D2n, r_ns * 64, Hn,
                             P.ref2 + (size_t)(r_bt * 64) * Tn * D2n + (size_t)pos * D2n + r_ns * 64,
                             (size_t)Tn * D2n, tid);
  };

  for (int t = 0; t < Tn; ++t) {
    const float* hprev = P.hbuf + (size_t)((t - 1) & 1) * (2 * Bn * Hn);
    if (t > 0) ref_job(hprev, r_dir ? (Tn - t) : (t - 1));
    floatx4 acc[4];
#pragma unroll
    for (int gg = 0; gg < 4; ++gg) acc[gg] = (floatx4){0.f, 0.f, 0.f, 0.f};
    if (t > 0)
      gates_gemm_v2(acc, smem, hprev + (size_t)dir * (Bn * Hn), Hn, Whh, Hn, Hn,
                    nullptr, 0, nullptr, 0, 0, btile * 64, hs * 16, tid);
    const int tcur = dir ? (Tn - 1 - t) : t;
    float xa[4], xb2[4];
#pragma unroll
    for (int r2 = 0; r2 < 4; ++r2) {
      const int m = btile * 64 + wave * 16 + quad * 4 + r2;
      xa[r2]  = P.inputs[(size_t)m * (Tn * 2) + tcur * 2 + 0];
      xb2[r2] = P.inputs[(size_t)m * (Tn * 2) + tcur * 2 + 1];
    }
    float gv[4][4];
#pragma unroll
    for (int gg = 0; gg < 4; ++gg) {
      const int grow = gg * Hn + hcol;
      const float bn = bias[grow];
      const float w20 = weff[grow * 2], w21 = weff[grow * 2 + 1];
#pragma unroll
      for (int r2 = 0; r2 < 4; ++r2) {
        float o = acc[gg][r2] + bn;
        o = fmaf(xa[r2], w20, fmaf(xb2[r2], w21, o));
        gv[gg][r2] = o;
      }
    }
    float* hdst = P.hbuf + (size_t)(t & 1) * (2 * Bn * Hn) + (size_t)dir * (Bn * Hn);
    const int tt = dir ? (Tn - 1 - t) : t;
#pragma unroll
    for (int r2 = 0; r2 < 4; ++r2) {
      const float cn = sigmoidf(gv[1][r2]) * c_reg[r2] +
                       sigmoidf(gv[0][r2]) * tanhf(gv[2][r2]);
      c_reg[r2] = cn;
      const float hn = sigmoidf(gv[3][r2]) * tanhf(cn);
      h_reg[r2] = hn;
      const int m = btile * 64 + wave * 16 + quad * 4 + r2;
      storef_dev(&hdst[(size_t)m * Hn + hcol], hn);
      store_dev<ET>(&P.Enc[(size_t)m * Tn * D2n + (size_t)tt * D2n + dir * Hn + hcol],
                    cvt_from_f<ET>(hn));
    }
    grid_sync256(P.flags, P.release, ++sync_no);
  }
  ref_job(P.hbuf + (size_t)1 * (2 * Bn * Hn), r_dir ? 0 : (Tn - 1));
#pragma unroll
  for (int r2 = 0; r2 < 4; ++r2) {
    const int m = btile * 64 + wave * 16 + quad * 4 + r2;
    P.dec_out0[(size_t)m * D2n + dir * Hn + hcol] = h_reg[r2];
    P.c_dec[((size_t)dir * Bn + m) * Hn + hcol] = c_reg[r2];
  }
}

// ---------------------------------------------------------------------------
// Persistent decoder: 512 blocks, 2/CU. P1/P2 on blocks <256 (same shapes as
// round 13); P3/P4 on all 512 (one b per block -> 2x waves on the big ref/Enc
// stream, the measured 862 GB/s bottleneck).
// ---------------------------------------------------------------------------
template<typename ET, typename RT1, typename RT2>
struct DecP {
  const int* test_roads;
  const float* Wih_f; const float* Whh_f; const float* b_f;
  const float* Wih_b; const float* Whh_b; const float* b_b;
  const float* W_q; const float* W_q2; const float* v; const float* v2;
  const ET* Enc; const RT1* ref1; const RT2* ref2;
  float* dec_out;
  float* xb;
  float* qb; float* q2b;
  const float* c_init;
  float* loss;
  unsigned* flags; unsigned* release;
};

template<typename ET, typename RT1, typename RT2>
__global__ __launch_bounds__(256, 2) void dec_coop(DecP<ET, RT1, RT2> P) {
  __shared__ __align__(16) short smem[16384];
  __shared__ float s1l[104], s2l[104], awl[104];
  __shared__ float redf[128];
  __shared__ int   redi[128];
  __shared__ float playedl[104];
  __shared__ float lossl;
  const int bid = blockIdx.x, tid = threadIdx.x;
  const int lane = tid & 63, wave = tid >> 6, qm = lane & 15, quad = lane >> 4;
  const bool p1 = bid < 256;
  const int dir = (bid >> 7) & 1, btile = (bid >> 4) & 7, hs = bid & 15;
  const int hcol = hs * 16 + qm;
  const float* Wih  = dir ? P.Wih_b : P.Wih_f;
  const float* Whh  = dir ? P.Whh_b : P.Whh_f;
  const float* bias = dir ? P.b_b : P.b_f;
  float c_reg[4] = {0.f, 0.f, 0.f, 0.f};
  if (p1) {
#pragma unroll
    for (int r2 = 0; r2 < 4; ++r2) {
      const int m = btile * 64 + wave * 16 + quad * 4 + r2;
      c_reg[r2] = P.c_init[((size_t)dir * Bn + m) * Hn + hcol];
    }
  }
  if (tid < Tn) playedl[tid] = 0.f;
  if (tid == 0) lossl = 0.f;
  const int proj = (bid >> 7) & 1, pbt = (bid >> 4) & 7, pn = bid & 15;
  const int attn = wave & 1, rh = wave >> 1;   // P3: (attn, row-half)
  const int b = bid;                           // one b per block
  unsigned sync_no = 0;
  __syncthreads();

  for (int t = 0; t < Tn; ++t) {
    const float* xc  = P.xb + (size_t)(t & 1) * (Bn * D2n);
    const float* dcur = P.dec_out + (size_t)(t & 1) * (Bn * D2n);
    float* dnext = P.dec_out + (size_t)((t + 1) & 1) * (Bn * D2n);
    // ---- P1: cell gates + LSTM (blocks < 256) ----
    if (p1) {
      floatx4 acc[4];
#pragma unroll
      for (int gg = 0; gg < 4; ++gg) acc[gg] = (floatx4){0.f, 0.f, 0.f, 0.f};
      gates_gemm_v2(acc, smem, xc, D2n, Wih, D2n, D2n,
                    dcur + dir * Hn, D2n, Whh, Hn, Hn, btile * 64, hs * 16, tid);
#pragma unroll
      for (int gg = 0; gg < 4; ++gg) {
        const float bn = bias[gg * Hn + hcol];
#pragma unroll
        for (int r2 = 0; r2 < 4; ++r2) acc[gg][r2] += bn;
      }
#pragma unroll
      for (int r2 = 0; r2 < 4; ++r2) {
        const float cn = sigmoidf(acc[1][r2]) * c_reg[r2] +
                         sigmoidf(acc[0][r2]) * tanhf(acc[2][r2]);
        c_reg[r2] = cn;
        const float hn = sigmoidf(acc[3][r2]) * tanhf(cn);
        const int m = btile * 64 + wave * 16 + quad * 4 + r2;
        storef_dev(&dnext[(size_t)m * D2n + dir * Hn + hcol], hn);
      }
    }
    grid_sync512(P.flags, P.release, ++sync_no);
    // ---- P2: q projections (blocks < 256, 64x32 tiles) ----
    if (p1) {
      const float* A = proj ? xc : dnext;
      const float* B = proj ? P.W_q2 : P.W_q;
      float* C = (proj ? P.q2b : P.qb) + (size_t)(pbt * 64) * D2n + pn * 32;
      gemm64v2<float, false, 2, true>(smem, A, D2n, pbt * 64, B, D2n, pn * 32, D2n,
                                      C, D2n, tid);
    }
    grid_sync512(P.flags, P.release, ++sync_no);
    // ---- P3: attention rows [rh*50, rh*50+50), 5-row ping-pong groups ----
    {
      const float* qrow = (attn ? P.q2b : P.qb) + (size_t)b * D2n;
      const float* vp = attn ? P.v2 : P.v;
      const int e0 = lane * 4, e1 = (64 + lane) * 4;
      const float4 q0 = load4_dev(qrow + e0);
      const float4 q1 = load4_dev(qrow + e1);
      const float4 v0 = *(const float4*)&vp[e0];
      const float4 v1 = *(const float4*)&vp[e1];
      float* sdst = attn ? s2l : s1l;
      const int jb0 = rh * 50;
      float4 Ra0[5], Ra1[5], Rb0[5], Rb1[5];
      auto ldg = [&](int jb, float4 (&R0)[5], float4 (&R1)[5]) {
#pragma unroll
        for (int jj = 0; jj < 5; ++jj) {
          if (attn == 0) {
            const RT1* row = P.ref1 + ((size_t)b * Tn + jb + jj) * D2n;
            R0[jj] = load4<RT1>(row + e0); R1[jj] = load4<RT1>(row + e1);
          } else {
            const RT2* row = P.ref2 + ((size_t)b * Tn + jb + jj) * D2n;
            R0[jj] = load4<RT2>(row + e0); R1[jj] = load4<RT2>(row + e1);
          }
        }
      };
      auto cmp = [&](int jb, const float4 (&R0)[5], const float4 (&R1)[5]) {
#pragma unroll
        for (int jj = 0; jj < 5; ++jj) {
          const float4 r0 = R0[jj], r1 = R1[jj];
          float a = 0.f;
          a = fmaf(fast_tanhf(r0.x + q0.x), v0.x, a);
          a = fmaf(fast_tanhf(r0.y + q0.y), v0.y, a);
          a = fmaf(fast_tanhf(r0.z + q0.z), v0.z, a);
          a = fmaf(fast_tanhf(r0.w + q0.w), v0.w, a);
          a = fmaf(fast_tanhf(r1.x + q1.x), v1.x, a);
          a = fmaf(fast_tanhf(r1.y + q1.y), v1.y, a);
          a = fmaf(fast_tanhf(r1.z + q1.z), v1.z, a);
          a = fmaf(fast_tanhf(r1.w + q1.w), v1.w, a);
#pragma unroll
          for (int off = 32; off > 0; off >>= 1) a += __shfl_xor(a, off, 64);
          if (lane == 0) sdst[jb + jj] = a;
        }
      };
      ldg(jb0, Ra0, Ra1);
      for (int g = 0; g < 10; g += 2) {
        if (g + 1 < 10) ldg(jb0 + (g + 1) * 5, Rb0, Rb1);
        cmp(jb0 + g * 5, Ra0, Ra1);
        if (g + 2 < 10) ldg(jb0 + (g + 2) * 5, Ra0, Ra1);
        if (g + 1 < 10) cmp(jb0 + (g + 1) * 5, Rb0, Rb1);
      }
    }
    __syncthreads();
    // ---- P4: one b, reductions on first 128 threads (tree identical to r13)
    {
      float* xnextbuf = P.xb + (size_t)((t + 1) & 1) * (Bn * D2n);
      const float uval = (tid < Tn) ? s2l[tid] : -INFINITY;
      const float owval = (tid < Tn) ? (s1l[tid] - PENf * playedl[tid])
                                     : -INFINITY;
      if (tid < 128) redf[tid] = uval;
      __syncthreads();
      for (int s = 64; s > 0; s >>= 1) {
        if (tid < s) redf[tid] = fmaxf(redf[tid], redf[tid + s]);
        __syncthreads();
      }
      const float umax = redf[0]; __syncthreads();
      const float e = (tid < Tn) ? __expf(uval - umax) : 0.f;
      if (tid < 128) redf[tid] = e;
      __syncthreads();
      for (int s = 64; s > 0; s >>= 1) {
        if (tid < s) redf[tid] += redf[tid + s];
        __syncthreads();
      }
      const float usum = redf[0]; __syncthreads();
      if (tid < Tn) awl[tid] = e / usum;
      if (tid < 128) { redf[tid] = owval; redi[tid] = (tid < Tn) ? tid : 0x7fffffff; }
      __syncthreads();
      for (int s = 64; s > 0; s >>= 1) {
        if (tid < s) {
          const float ov = redf[tid + s]; const int oi = redi[tid + s];
          if (ov > redf[tid] || (ov == redf[tid] && oi < redi[tid])) {
            redf[tid] = ov; redi[tid] = oi;
          }
        }
        __syncthreads();
      }
      const float omax = redf[0]; const int sel = redi[0]; __syncthreads();
      const float eo = (tid < Tn) ? __expf(owval - omax) : 0.f;
      if (tid < 128) redf[tid] = eo;
      __syncthreads();
      for (int s = 64; s > 0; s >>= 1) {
        if (tid < s) redf[tid] += redf[tid + s];
        __syncthreads();
      }
      if (tid == 0) {
        const float lse = omax + __logf(redf[0]);
        const int tgt = P.test_roads[b * Tn + t];
        const float owt = s1l[tgt] - PENf * playedl[tgt];
        lossl += lse - owt;
        playedl[sel] += 1.f;
      }
      __syncthreads();
      // x_new: 256 threads x 2 cols, 10-row groups, same per-column j order
      const ET* Eb = P.Enc + (size_t)b * Tn * D2n;
      float* xn = xnextbuf + (size_t)b * D2n;
      const int k2 = tid * 2;
      float2 Ea[10], Eb2[10];
      auto lde = [&](int jb, float2 (&E)[10]) {
#pragma unroll
        for (int jj = 0; jj < 10; ++jj)
          E[jj] = load2h(Eb + (size_t)(jb + jj) * D2n + k2);
      };
      float2 a2 = {0.f, 0.f};
      auto ac2 = [&](int jb, const float2 (&E)[10]) {
#pragma unroll
        for (int jj = 0; jj < 10; ++jj) {
          const float w = awl[jb + jj];
          a2.x = fmaf(w, E[jj].x, a2.x);
          a2.y = fmaf(w, E[jj].y, a2.y);
        }
      };
      lde(0, Ea);
      for (int g = 0; g < 10; g += 2) {
        if (g + 1 < 10) lde((g + 1) * 10, Eb2);
        ac2(g * 10, Ea);
        if (g + 2 < 10) lde((g + 2) * 10, Ea);
        if (g + 1 < 10) ac2((g + 1) * 10, Eb2);
      }
      store2_dev(&xn[k2], a2);
    }
    grid_sync512(P.flags, P.release, ++sync_no);
  }
  if (tid == 0) P.loss[bid] = lossl;
}

// ---------------------------------------------------------------------------
static void run_all(void* const* d_in, void* d_out, char* ws, hipStream_t stream) {
  using ET = __half; using RT1 = __half; using RT2 = __half;
  const float* inputs     = (const float*)d_in[0];
  const int*   test_roads = (const int*)d_in[1];
  const float* W_embed    = (const float*)d_in[2];
  const float* enc_Wih_f  = (const float*)d_in[3];
  const float* enc_Whh_f  = (const float*)d_in[4];
  const float* enc_b_f    = (const float*)d_in[5];
  const float* enc_Wih_b  = (const float*)d_in[6];
  const float* enc_Whh_b  = (const float*)d_in[7];
  const float* enc_b_b    = (const float*)d_in[8];
  const float* dec_Wih_f  = (const float*)d_in[9];
  const float* dec_Whh_f  = (const float*)d_in[10];
  const float* dec_b_f    = (const float*)d_in[11];
  const float* dec_Wih_b  = (const float*)d_in[12];
  const float* dec_Whh_b  = (const float*)d_in[13];
  const float* dec_b_b    = (const float*)d_in[14];
  const float* W_ref      = (const float*)d_in[15];
  const float* W_q        = (const float*)d_in[16];
  const float* v          = (const float*)d_in[17];
  const float* W_ref2     = (const float*)d_in[18];
  const float* W_q2       = (const float*)d_in[19];
  const float* v2         = (const float*)d_in[20];

  char* p0 = ws;
  ET*  Enc  = (ET*)p0;  p0 += BIGN * sizeof(ET);
  RT1* ref1 = (RT1*)p0; p0 += BIGN * sizeof(RT1);
  RT2* ref2 = (RT2*)p0; p0 += BIGN * sizeof(RT2);
  unsigned* flagsE = (unsigned*)p0;                 // 256 padded lines
  unsigned* relE   = flagsE + 256 * FLAG_STRIDE;
  unsigned* flagsD = relE + 32;                     // 512 padded lines
  unsigned* relD   = flagsD + 512 * FLAG_STRIDE;
  float* xb      = (float*)(p0 + BAR_UINTS * 4);
  float* dec_out = xb + 2 * Bn * D2n;
  float* hbuf    = dec_out + 2 * Bn * D2n;
  float* c_dec   = hbuf + 4 * Bn * Hn;
  float* qb      = c_dec + 2 * Bn * Hn;
  float* q2b     = qb + Bn * D2n;
  float* weff_f  = q2b + Bn * D2n;
  float* weff_b  = weff_f + G4n * 2;

  hipMemsetAsync(ref1, 0, BIGN * (sizeof(RT1) + sizeof(RT2)), stream);
  hipMemsetAsync(flagsE, 0, BAR_UINTS * 4 + (size_t)Bn * D2n * 4, stream);

  weff_kernel<<<G4n / 256, 256, 0, stream>>>(enc_Wih_f, enc_Wih_b, W_embed,
                                             weff_f, weff_b);

  EncP<ET, RT1, RT2> ep = { inputs, enc_Whh_f, enc_Whh_b, enc_b_f, enc_b_b,
                            weff_f, weff_b, W_ref, W_ref2,
                            hbuf, c_dec, dec_out, Enc, ref1, ref2,
                            flagsE, relE };
  enc_coop<ET, RT1, RT2><<<256, 256, 0, stream>>>(ep);

  DecP<ET, RT1, RT2> dp = { test_roads,
                            dec_Wih_f, dec_Whh_f, dec_b_f,
                            dec_Wih_b, dec_Whh_b, dec_b_b,
                            W_q, W_q2, v, v2,
                            Enc, ref1, ref2,
                            dec_out, xb, qb, q2b, c_dec,
                            (float*)d_out, flagsD, relD };
  dec_coop<ET, RT1, RT2><<<512, 256, 0, stream>>>(dp);
}

// ---------------------------------------------------------------------------
extern "C" void kernel_launch(void* const* d_in, const int* in_sizes, int n_in,
                              void* d_out, int out_size, void* d_ws, size_t ws_size,
                              hipStream_t stream) {
  (void)in_sizes; (void)n_in; (void)out_size; (void)ws_size;
  run_all(d_in, d_out, (char*)d_ws, stream);
}